// Round 3
// baseline (886.473 us; speedup 1.0000x reference)
//
#include <hip/hip_runtime.h>
#include <hip/hip_bf16.h>
#include <math.h>

#define SQRT8_INV  0.35355339059327373f   // 1/sqrt(8)
#define H_SCALE    0.04419417382415922f   // 0.25/sqrt(32)
#define FAN_SC     0.04419417382415922f   // 1/sqrt(32*16)
#define W1_SCALE   0.125f                 // 1/sqrt(64)
#define LIN2_SCALE 0.125f                 // 1/sqrt(64)
#define SQ3_INVF   0.57735026918962576f   // 1/sqrt(3)

__device__ __forceinline__ unsigned pack_bf16(float a, float b) {
    unsigned ua = __float_as_uint(a);
    ua += 0x7FFFu + ((ua >> 16) & 1u);          // RNE
    unsigned ub = __float_as_uint(b);
    ub += 0x7FFFu + ((ub >> 16) & 1u);
    return (ua >> 16) | (ub & 0xFFFF0000u);
}
__device__ __forceinline__ float bf_lo(unsigned u) { return __uint_as_float(u << 16); }
__device__ __forceinline__ float bf_hi(unsigned u) { return __uint_as_float(u & 0xFFFF0000u); }

// ---------------- zero int buffer ----------------
__global__ __launch_bounds__(256) void zero_int(int* __restrict__ p, int n) {
    int i = blockIdx.x * 256 + threadIdx.x;
    if (i < n) p[i] = 0;
}

// ---------------- w1 -> w1x[c][j][4]  (for mlp_kernel, s_load stream) ----------------
__global__ __launch_bounds__(256) void prep_w1x(const float* __restrict__ w1,
                                                float* __restrict__ w1x) {
    int idx = blockIdx.x * 256 + threadIdx.x;   // 0 .. 8191
    if (idx >= 128 * 64) return;
    int c = idx >> 6, j = idx & 63;
    #pragma unroll
    for (int q = 0; q < 4; ++q)
        w1x[(idx << 2) + q] = w1[j * 128 + q * 32 + c];
}

// ---------------- w1 -> w1p (fallback gather path, per-thread float2) ----------------
__global__ __launch_bounds__(256) void prep_w1p(const float* __restrict__ w1,
                                                float* __restrict__ w1p) {
    int idx = blockIdx.x * 256 + threadIdx.x;
    if (idx >= 64 * 64) return;
    int j = idx >> 6, t = idx & 63;
    int colA = (t < 32) ? t : t + 32;
    int colB = (t < 32) ? t + 32 : t + 64;
    w1p[idx * 2 + 0] = w1[j * 128 + colA];
    w1p[idx * 2 + 1] = w1[j * 128 + colB];
}

// ---------------- histogram of edge_dst ----------------
__global__ __launch_bounds__(256) void hist_kernel(const int* __restrict__ eidx,
                                                   int* __restrict__ cnt, int E) {
    int e = blockIdx.x * 256 + threadIdx.x;
    if (e < E) atomicAdd(&cnt[eidx[e]], 1);
}

// ---------------- exclusive scan of counts (single block) ----------------
__global__ __launch_bounds__(1024) void scan_kernel(const int* __restrict__ cnt,
                                                    int* __restrict__ off,
                                                    int* __restrict__ cur, int N) {
    __shared__ int sums[1024];
    int t = threadIdx.x;
    int chunk = (N + 1023) >> 10;
    int lo = t * chunk, hi = min(lo + chunk, N);
    int s = 0;
    for (int i = lo; i < hi; ++i) s += cnt[i];
    sums[t] = s;
    __syncthreads();
    for (int d = 1; d < 1024; d <<= 1) {
        int v = (t >= d) ? sums[t - d] : 0;
        __syncthreads();
        sums[t] += v;
        __syncthreads();
    }
    int base = (t == 0) ? 0 : sums[t - 1];
    for (int i = lo; i < hi; ++i) { off[i] = base; cur[i] = base; base += cnt[i]; }
    if (t == 1023) off[N] = sums[1023];
}

// ---------------- scatter edge ids into dst-sorted order ----------------
__global__ __launch_bounds__(256) void scatter_kernel(const int* __restrict__ eidx,
                                                      int* __restrict__ cur,
                                                      int* __restrict__ order, int E) {
    int e = blockIdx.x * 256 + threadIdx.x;
    if (e >= E) return;
    int pos = atomicAdd(&cur[eidx[e]], 1);
    order[pos] = e;
}

// ---------------- node stage: h (lin1, interleaved float4) + sc into out ----------------
__global__ __launch_bounds__(128) void node_kernel(
    const float* __restrict__ nf, const float* __restrict__ attrs,
    const float* __restrict__ l1w0, const float* __restrict__ l1w1,
    const float* __restrict__ scw0, const float* __restrict__ scw1,
    float* __restrict__ h4, float* __restrict__ out) {
    int n = blockIdx.x;
    int t = threadIdx.x;
    __shared__ float x[128];
    __shared__ int vs;
    x[t] = nf[n * 128 + t];
    if (t < 16) {
        if (attrs[n * 16 + t] > 0.5f) vs = t;   // one-hot: exactly one writer
    }
    __syncthreads();
    int v = vs;
    if (t < 32) {
        int w = t;
        float a = 0.f, b = 0.f;
        #pragma unroll
        for (int u = 0; u < 32; ++u) {
            float xv = x[u];
            a = fmaf(xv, l1w0[u * 32 + w], a);
            b = fmaf(xv, scw0[u * 512 + v * 32 + w], b);
        }
        h4[n * 128 + w * 4] = a * H_SCALE;
        out[n * 128 + w]    = b * FAN_SC;
    } else {
        int j = t - 32;                // 0..95
        int vch = j / 3, m = j - vch * 3;
        float a = 0.f, b = 0.f;
        #pragma unroll
        for (int u = 0; u < 32; ++u) {
            float xv = x[32 + u * 3 + m];
            a = fmaf(xv, l1w1[u * 32 + vch], a);
            b = fmaf(xv, scw1[u * 512 + v * 32 + vch], b);
        }
        h4[n * 128 + vch * 4 + 1 + m]   = a * H_SCALE;
        out[n * 128 + 32 + vch * 3 + m] = b * FAN_SC;
    }
}

// ---------------- edge MLP: one thread per SORTED edge slot, w -> bf16 packed ----------------
__global__ __launch_bounds__(256, 1) void mlp_kernel(
    const float* __restrict__ ee, const int* __restrict__ order,
    const float* __restrict__ w0, const float* __restrict__ w1x,
    uint2* __restrict__ ws2, int E) {
    int i = blockIdx.x * 256 + threadIdx.x;
    if (i >= E) return;
    int e = order[i];

    const float4* eep = (const float4*)ee;
    float4 e0 = eep[(size_t)e * 2], e1 = eep[(size_t)e * 2 + 1];
    float eev[8];
    eev[0] = e0.x * SQRT8_INV; eev[1] = e0.y * SQRT8_INV;
    eev[2] = e0.z * SQRT8_INV; eev[3] = e0.w * SQRT8_INV;
    eev[4] = e1.x * SQRT8_INV; eev[5] = e1.y * SQRT8_INV;
    eev[6] = e1.z * SQRT8_INV; eev[7] = e1.w * SQRT8_INV;

    float hid[64];
    #pragma unroll
    for (int j = 0; j < 64; ++j) {
        float a = 0.f;
        #pragma unroll
        for (int k = 0; k < 8; ++k) a = fmaf(eev[k], w0[k * 64 + j], a);
        float s = 1.f / (1.f + __expf(-a));
        hid[j] = a * s * W1_SCALE;
    }

    for (int c = 0; c < 32; ++c) {
        const float4* wp = (const float4*)(w1x + c * 256);  // uniform -> s_load
        float wa = 0.f, wb = 0.f, wc_ = 0.f, wd = 0.f;
        #pragma unroll
        for (int j = 0; j < 64; ++j) {
            float4 wv = wp[j];
            float hj = hid[j];
            wa  = fmaf(hj, wv.x, wa);
            wb  = fmaf(hj, wv.y, wb);
            wc_ = fmaf(hj, wv.z, wc_);
            wd  = fmaf(hj, wv.w, wd);
        }
        ws2[(size_t)i * 32 + c] = make_uint2(pack_bf16(wa, wb), pack_bf16(wc_, wd));
    }
}

// ---------------- reduce: 4 nodes / 256-thr block, stream sorted w, fused lin2 ----------------
__global__ __launch_bounds__(256) void reduce_kernel(
    const unsigned* __restrict__ wsu, const float4* __restrict__ eattr4,
    const int* __restrict__ eidx, const int* __restrict__ order,
    const int* __restrict__ off, const float4* __restrict__ h4,
    const float* __restrict__ l2w0, const float* __restrict__ l2w1,
    float* __restrict__ out, int N, int E) {
    int w = threadIdx.x >> 6, t = threadIdx.x & 63;
    int n = blockIdx.x * 4 + w;
    __shared__ float ld[4][256];
    int c = t & 31;
    int half = t >> 5;                  // 0: (wa,wb)  1: (wc,wd)
    float acc0 = 0.f, acc1 = 0.f, acc2 = 0.f, acc3 = 0.f;

    if (n < N) {
        int beg = off[n], end = off[n + 1];
        for (int i = beg; i < end; ++i) {
            int e = order[i];
            int src = eidx[E + e];
            float4 ea = eattr4[e];
            unsigned wu = wsu[(size_t)i * 64 + c * 2 + half];
            float wA = bf_lo(wu), wB = bf_hi(wu);
            float4 xs = h4[(size_t)src * 32 + c];
            if (half == 0) {
                acc0 = fmaf(wA * xs.x, ea.x, acc0);          // m0a
                float bx = wB * xs.x;
                acc1 = fmaf(bx, ea.y, acc1);                 // m1a
                acc2 = fmaf(bx, ea.z, acc2);
                acc3 = fmaf(bx, ea.w, acc3);
            } else {
                float dv = xs.y * ea.y + xs.z * ea.z + xs.w * ea.w;
                acc0 = fmaf(wB * SQ3_INVF, dv, acc0);        // m0b
                float cy = wA * ea.x;
                acc1 = fmaf(cy, xs.y, acc1);                 // m1b
                acc2 = fmaf(cy, xs.z, acc2);
                acc3 = fmaf(cy, xs.w, acc3);
            }
        }
        if (half == 0) {
            ld[w][c] = acc0;
            ld[w][64 + c * 3 + 0] = acc1;
            ld[w][64 + c * 3 + 1] = acc2;
            ld[w][64 + c * 3 + 2] = acc3;
        } else {
            ld[w][32 + c] = acc0;
            ld[w][160 + c * 3 + 0] = acc1;
            ld[w][160 + c * 3 + 1] = acc2;
            ld[w][160 + c * 3 + 2] = acc3;
        }
    }
    __syncthreads();
    if (n < N) {
        #pragma unroll
        for (int hh = 0; hh < 2; ++hh) {
            int j = t + hh * 64;
            float acc = 0.f;
            if (j < 32) {
                #pragma unroll
                for (int u = 0; u < 64; ++u) acc = fmaf(ld[w][u], l2w0[u * 32 + j], acc);
            } else {
                int jj = j - 32, vch = jj / 3, m = jj - vch * 3;
                #pragma unroll
                for (int u = 0; u < 64; ++u) acc = fmaf(ld[w][64 + u * 3 + m], l2w1[u * 32 + vch], acc);
            }
            out[(size_t)n * 128 + j] += acc * LIN2_SCALE;
        }
    }
}

// ---------------- FALLBACK (ws too small): round-2 fused gather ----------------
__global__ __launch_bounds__(64) void gather_kernel(
    const float* __restrict__ ee, const float4* __restrict__ eattr4,
    const int* __restrict__ eidx, const int* __restrict__ order,
    const int* __restrict__ off,
    const float* __restrict__ w0, const float2* __restrict__ w1p2,
    const float4* __restrict__ h4,
    const float* __restrict__ l2w0, const float* __restrict__ l2w1,
    float* __restrict__ out, int E) {
    int n = blockIdx.x, t = threadIdx.x;
    int beg = off[n], end = off[n + 1];
    __shared__ float s_ee[8];
    __shared__ float s_hid[64];
    __shared__ float ld[256];
    float acc0 = 0.f, acc1 = 0.f, acc2 = 0.f, acc3 = 0.f;
    int c = t & 31;
    for (int i = beg; i < end; ++i) {
        int e = order[i];
        int src = eidx[E + e];
        if (t < 8) s_ee[t] = ee[e * 8 + t] * SQRT8_INV;
        __syncthreads();
        float a = 0.f;
        #pragma unroll
        for (int k = 0; k < 8; ++k) a = fmaf(s_ee[k], w0[k * 64 + t], a);
        float sg = 1.f / (1.f + __expf(-a));
        __syncthreads();
        s_hid[t] = a * sg * W1_SCALE;
        __syncthreads();
        float wA = 0.f, wB = 0.f;
        #pragma unroll
        for (int j = 0; j < 64; ++j) {
            float2 wv = w1p2[j * 64 + t];
            float hj = s_hid[j];
            wA = fmaf(hj, wv.x, wA);
            wB = fmaf(hj, wv.y, wB);
        }
        float4 xs = h4[(size_t)src * 32 + c];
        float4 ea = eattr4[e];
        if (t < 32) {
            acc0 = fmaf(wA * xs.x, ea.x, acc0);
            float bx = wB * xs.x;
            acc1 = fmaf(bx, ea.y, acc1);
            acc2 = fmaf(bx, ea.z, acc2);
            acc3 = fmaf(bx, ea.w, acc3);
        } else {
            float dv = xs.y * ea.y + xs.z * ea.z + xs.w * ea.w;
            acc0 = fmaf(wB * SQ3_INVF, dv, acc0);
            float cy = wA * ea.x;
            acc1 = fmaf(cy, xs.y, acc1);
            acc2 = fmaf(cy, xs.z, acc2);
            acc3 = fmaf(cy, xs.w, acc3);
        }
    }
    if (t < 32) {
        ld[t] = acc0;
        ld[64 + t * 3 + 0] = acc1;
        ld[64 + t * 3 + 1] = acc2;
        ld[64 + t * 3 + 2] = acc3;
    } else {
        int cc = t - 32;
        ld[32 + cc] = acc0;
        ld[160 + cc * 3 + 0] = acc1;
        ld[160 + cc * 3 + 1] = acc2;
        ld[160 + cc * 3 + 2] = acc3;
    }
    __syncthreads();
    #pragma unroll
    for (int hh = 0; hh < 2; ++hh) {
        int j = t + hh * 64;
        float acc = 0.f;
        if (j < 32) {
            #pragma unroll
            for (int u = 0; u < 64; ++u) acc = fmaf(ld[u], l2w0[u * 32 + j], acc);
        } else {
            int jj = j - 32, vch = jj / 3, m = jj - vch * 3;
            #pragma unroll
            for (int u = 0; u < 64; ++u) acc = fmaf(ld[64 + u * 3 + m], l2w1[u * 32 + vch], acc);
        }
        out[(size_t)n * 128 + j] += acc * LIN2_SCALE;
    }
}

extern "C" void kernel_launch(void* const* d_in, const int* in_sizes, int n_in,
                              void* d_out, int out_size, void* d_ws, size_t ws_size,
                              hipStream_t stream) {
    const float* nf    = (const float*)d_in[0];
    const float* attrs = (const float*)d_in[1];
    const float* eattr = (const float*)d_in[2];
    const float* ee    = (const float*)d_in[3];
    const int*   eidx  = (const int*)d_in[4];
    const float* l1w0  = (const float*)d_in[5];
    const float* l1w1  = (const float*)d_in[6];
    const float* w0    = (const float*)d_in[7];
    const float* w1    = (const float*)d_in[8];
    const float* l2w0  = (const float*)d_in[9];
    const float* l2w1  = (const float*)d_in[10];
    const float* scw0  = (const float*)d_in[11];
    const float* scw1  = (const float*)d_in[12];

    int N = in_sizes[0] / 128;
    int E = in_sizes[3] / 8;

    // ws layout: h4 | w1x | w1p | cnt | off | cur | order | wsu(bf16 w, sorted)
    float* h4    = (float*)d_ws;                       // N*128
    float* w1x   = h4 + (size_t)N * 128;               // 8192
    float* w1p   = w1x + 8192;                         // 8192
    int*   cnt   = (int*)(w1p + 8192);                 // N
    int*   off   = cnt + N;                            // N+1
    int*   cur   = off + N + 1;                        // N
    int*   order = cur + N;                            // E
    unsigned* wsu = (unsigned*)(order + E);            // E*64 uints

    size_t need = ((size_t)N * 128 + 16384 + 3 * (size_t)N + 1 + (size_t)E) * 4
                + (size_t)E * 256;
    bool big = ws_size >= need;

    zero_int<<<(N + 255) / 256, 256, 0, stream>>>(cnt, N);
    hist_kernel<<<(E + 255) / 256, 256, 0, stream>>>(eidx, cnt, E);
    scan_kernel<<<1, 1024, 0, stream>>>(cnt, off, cur, N);
    scatter_kernel<<<(E + 255) / 256, 256, 0, stream>>>(eidx, cur, order, E);
    node_kernel<<<N, 128, 0, stream>>>(nf, attrs, l1w0, l1w1, scw0, scw1, h4, (float*)d_out);

    if (big) {
        prep_w1x<<<32, 256, 0, stream>>>(w1, w1x);
        mlp_kernel<<<(E + 255) / 256, 256, 0, stream>>>(ee, order, w0, w1x,
                                                        (uint2*)wsu, E);
        reduce_kernel<<<(N + 3) / 4, 256, 0, stream>>>(wsu, (const float4*)eattr,
                                                       eidx, order, off,
                                                       (const float4*)h4,
                                                       l2w0, l2w1, (float*)d_out, N, E);
    } else {
        prep_w1p<<<16, 256, 0, stream>>>(w1, w1p);
        gather_kernel<<<N, 64, 0, stream>>>(ee, (const float4*)eattr, eidx, order, off,
                                            w0, (const float2*)w1p, (const float4*)h4,
                                            l2w0, l2w1, (float*)d_out, E);
    }
}

// Round 4
// 728.151 us; speedup vs baseline: 1.2174x; 1.2174x over previous
//
#include <hip/hip_runtime.h>
#include <math.h>

#define SQRT8_INV  0.35355339059327373f   // 1/sqrt(8)
#define H_SCALE    0.04419417382415922f   // 0.25/sqrt(32)
#define FAN_SC     0.04419417382415922f   // 1/sqrt(32*16)
#define W1_SCALE   0.125f                 // 1/sqrt(64)
#define LIN2_SCALE 0.125f                 // 1/sqrt(64)
#define SQ3_INVF   0.57735026918962576f   // 1/sqrt(3)

// record layout per sorted edge slot: 320 B = 80 uints
//   [0..63]  w as bf16 pairs: uint 2c   = pack(wa,wb), 2c+1 = pack(wc,wd)
//   [64..67] eattr float4
//   [68]     src node id
//   [69..79] pad (keeps every record 5 full 64B lines -> aligned tile flushes)
#define REC_U 80
#define REC_B 320

__device__ __forceinline__ unsigned pack_bf16(float a, float b) {
    unsigned ua = __float_as_uint(a);
    ua += 0x7FFFu + ((ua >> 16) & 1u);          // RNE
    unsigned ub = __float_as_uint(b);
    ub += 0x7FFFu + ((ub >> 16) & 1u);
    return (ua >> 16) | (ub & 0xFFFF0000u);
}
__device__ __forceinline__ float bf_lo(unsigned u) { return __uint_as_float(u << 16); }
__device__ __forceinline__ float bf_hi(unsigned u) { return __uint_as_float(u & 0xFFFF0000u); }

// ---------------- zero int buffer ----------------
__global__ __launch_bounds__(256) void zero_int(int* __restrict__ p, int n) {
    int i = blockIdx.x * 256 + threadIdx.x;
    if (i < n) p[i] = 0;
}

// ---------------- w1 -> w1x[c][j][4]  (s_load stream for mlp) ----------------
__global__ __launch_bounds__(256) void prep_w1x(const float* __restrict__ w1,
                                                float* __restrict__ w1x) {
    int idx = blockIdx.x * 256 + threadIdx.x;   // 0 .. 8191
    if (idx >= 128 * 64) return;
    int c = idx >> 6, j = idx & 63;
    #pragma unroll
    for (int q = 0; q < 4; ++q)
        w1x[(idx << 2) + q] = w1[j * 128 + q * 32 + c];
}

// ---------------- w1 -> w1p (fallback gather path) ----------------
__global__ __launch_bounds__(256) void prep_w1p(const float* __restrict__ w1,
                                                float* __restrict__ w1p) {
    int idx = blockIdx.x * 256 + threadIdx.x;
    if (idx >= 64 * 64) return;
    int j = idx >> 6, t = idx & 63;
    int colA = (t < 32) ? t : t + 32;
    int colB = (t < 32) ? t + 32 : t + 64;
    w1p[idx * 2 + 0] = w1[j * 128 + colA];
    w1p[idx * 2 + 1] = w1[j * 128 + colB];
}

// ---------------- histogram of edge_dst ----------------
__global__ __launch_bounds__(256) void hist_kernel(const int* __restrict__ eidx,
                                                   int* __restrict__ cnt, int E) {
    int e = blockIdx.x * 256 + threadIdx.x;
    if (e < E) atomicAdd(&cnt[eidx[e]], 1);
}

// ---------------- exclusive scan of counts (single block) ----------------
__global__ __launch_bounds__(1024) void scan_kernel(const int* __restrict__ cnt,
                                                    int* __restrict__ off,
                                                    int* __restrict__ cur, int N) {
    __shared__ int sums[1024];
    int t = threadIdx.x;
    int chunk = (N + 1023) >> 10;
    int lo = t * chunk, hi = min(lo + chunk, N);
    int s = 0;
    for (int i = lo; i < hi; ++i) s += cnt[i];
    sums[t] = s;
    __syncthreads();
    for (int d = 1; d < 1024; d <<= 1) {
        int v = (t >= d) ? sums[t - d] : 0;
        __syncthreads();
        sums[t] += v;
        __syncthreads();
    }
    int base = (t == 0) ? 0 : sums[t - 1];
    for (int i = lo; i < hi; ++i) { off[i] = base; cur[i] = base; base += cnt[i]; }
    if (t == 1023) off[N] = sums[1023];
}

// ---------------- scatter edge ids into dst-sorted order ----------------
__global__ __launch_bounds__(256) void scatter_kernel(const int* __restrict__ eidx,
                                                      int* __restrict__ cur,
                                                      int* __restrict__ order, int E) {
    int e = blockIdx.x * 256 + threadIdx.x;
    if (e >= E) return;
    int pos = atomicAdd(&cur[eidx[e]], 1);
    order[pos] = e;
}

// ---------------- node stage: h (lin1, interleaved float4) + sc into out ----------------
__global__ __launch_bounds__(128) void node_kernel(
    const float* __restrict__ nf, const float* __restrict__ attrs,
    const float* __restrict__ l1w0, const float* __restrict__ l1w1,
    const float* __restrict__ scw0, const float* __restrict__ scw1,
    float* __restrict__ h4, float* __restrict__ out) {
    int n = blockIdx.x;
    int t = threadIdx.x;
    __shared__ float x[128];
    __shared__ int vs;
    x[t] = nf[n * 128 + t];
    if (t < 16) {
        if (attrs[n * 16 + t] > 0.5f) vs = t;   // one-hot: exactly one writer
    }
    __syncthreads();
    int v = vs;
    if (t < 32) {
        int w = t;
        float a = 0.f, b = 0.f;
        #pragma unroll
        for (int u = 0; u < 32; ++u) {
            float xv = x[u];
            a = fmaf(xv, l1w0[u * 32 + w], a);
            b = fmaf(xv, scw0[u * 512 + v * 32 + w], b);
        }
        h4[n * 128 + w * 4] = a * H_SCALE;
        out[n * 128 + w]    = b * FAN_SC;
    } else {
        int j = t - 32;                // 0..95
        int vch = j / 3, m = j - vch * 3;
        float a = 0.f, b = 0.f;
        #pragma unroll
        for (int u = 0; u < 32; ++u) {
            float xv = x[32 + u * 3 + m];
            a = fmaf(xv, l1w1[u * 32 + vch], a);
            b = fmaf(xv, scw1[u * 512 + v * 32 + vch], b);
        }
        h4[n * 128 + vch * 4 + 1 + m]   = a * H_SCALE;
        out[n * 128 + 32 + vch * 3 + m] = b * FAN_SC;
    }
}

// ---------------- edge MLP: lane-per-edge, LDS-staged COALESCED record writes ----------------
__global__ __launch_bounds__(256) void mlp_kernel(
    const float* __restrict__ ee, const float4* __restrict__ eattr4,
    const int* __restrict__ eidx, const int* __restrict__ order,
    const float* __restrict__ w0, const float* __restrict__ w1x,
    unsigned* __restrict__ rec, int base, int len, int E) {
    __shared__ unsigned lbuf[4][64 * 17];   // per-wave region, 17-uint row stride (bank-spread)
    int tid  = threadIdx.x;
    int wid  = tid >> 6, lane = tid & 63;
    int idx  = blockIdx.x * 256 + tid;      // record index within segment
    bool valid = idx < len;

    int src = 0;
    float4 ea = make_float4(0.f, 0.f, 0.f, 0.f);
    float hid[64];
    if (valid) {
        int e = order[base + idx];
        src = eidx[E + e];
        ea  = eattr4[e];
        const float4* eep = (const float4*)ee;
        float4 e0 = eep[(size_t)e * 2], e1 = eep[(size_t)e * 2 + 1];
        float eev[8];
        eev[0] = e0.x * SQRT8_INV; eev[1] = e0.y * SQRT8_INV;
        eev[2] = e0.z * SQRT8_INV; eev[3] = e0.w * SQRT8_INV;
        eev[4] = e1.x * SQRT8_INV; eev[5] = e1.y * SQRT8_INV;
        eev[6] = e1.z * SQRT8_INV; eev[7] = e1.w * SQRT8_INV;
        #pragma unroll
        for (int j = 0; j < 64; ++j) {
            float a = 0.f;
            #pragma unroll
            for (int k = 0; k < 8; ++k) a = fmaf(eev[k], w0[k * 64 + j], a);
            float s = 1.f / (1.f + __expf(-a));
            hid[j] = a * s * W1_SCALE;
        }
    } else {
        #pragma unroll
        for (int j = 0; j < 64; ++j) hid[j] = 0.f;
    }

    unsigned* row = &lbuf[wid][lane * 17];
    int wavebase = blockIdx.x * 256 + wid * 64;   // record idx of this wave's lane 0

    for (int ct = 0; ct < 4; ++ct) {              // 8 channels per tile
        #pragma unroll
        for (int cc = 0; cc < 8; ++cc) {
            int c = ct * 8 + cc;
            const float4* wp = (const float4*)(w1x + c * 256);  // uniform -> s_load
            float wa = 0.f, wb = 0.f, wc_ = 0.f, wd = 0.f;
            #pragma unroll
            for (int j = 0; j < 64; ++j) {
                float4 wv = wp[j];
                float hj = hid[j];
                wa  = fmaf(hj, wv.x, wa);
                wb  = fmaf(hj, wv.y, wb);
                wc_ = fmaf(hj, wv.z, wc_);
                wd  = fmaf(hj, wv.w, wd);
            }
            row[cc * 2]     = pack_bf16(wa, wb);
            row[cc * 2 + 1] = pack_bf16(wc_, wd);
        }
        __syncthreads();
        // flush: 4 lanes cover one edge's 64B chunk -> every HBM line written once, fully
        #pragma unroll
        for (int s = 0; s < 4; ++s) {
            int il = s * 16 + (lane >> 2);
            int ridx = wavebase + il;
            if (ridx < len) {
                const unsigned* p = &lbuf[wid][il * 17 + (lane & 3) * 4];
                uint4 v = make_uint4(p[0], p[1], p[2], p[3]);
                *(uint4*)((char*)rec + (size_t)ridx * REC_B + ct * 64 + (lane & 3) * 16) = v;
            }
        }
        __syncthreads();
    }
    if (valid) {
        unsigned* myrec = rec + (size_t)idx * REC_U;
        *(float4*)(myrec + 64) = ea;
        ((int*)myrec)[68] = src;
    }
}

// ---------------- reduce: sequential record stream + h4 gather, fused lin2 ----------------
__global__ __launch_bounds__(256) void reduce_kernel(
    const unsigned* __restrict__ rec, const int* __restrict__ off,
    const float4* __restrict__ h4,
    const float* __restrict__ l2w0, const float* __restrict__ l2w1,
    float* __restrict__ out, int N, int base, int len) {
    int w = threadIdx.x >> 6, t = threadIdx.x & 63;
    int n = blockIdx.x * 4 + w;
    __shared__ float ld[4][256];
    int c = t & 31;
    int half = t >> 5;
    int kk = c * 2 + half;
    float acc0 = 0.f, acc1 = 0.f, acc2 = 0.f, acc3 = 0.f;

    int beg = 0, end = 0;
    if (n < N) {
        beg = max(off[n], base);
        end = min(off[n + 1], base + len);
    }

    // software pipeline: depth-2 record fields, depth-1 h4 gather
    unsigned wuA = 0, wuB = 0;
    float4 eaA = make_float4(0.f,0.f,0.f,0.f), eaB = eaA;
    int srcA = 0, srcB = 0;
    float4 xsA = make_float4(0.f,0.f,0.f,0.f);
    if (beg < end) {
        const unsigned* r = rec + (size_t)(beg - base) * REC_U;
        wuA = r[kk]; eaA = *(const float4*)(r + 64); srcA = ((const int*)r)[68];
        xsA = h4[(size_t)srcA * 32 + c];
        if (beg + 1 < end) {
            const unsigned* r1 = rec + (size_t)(beg + 1 - base) * REC_U;
            wuB = r1[kk]; eaB = *(const float4*)(r1 + 64); srcB = ((const int*)r1)[68];
        }
    }
    for (int i = beg; i < end; ++i) {
        unsigned wuT = 0; float4 eaT = make_float4(0.f,0.f,0.f,0.f); int srcT = 0;
        if (i + 2 < end) {
            const unsigned* r = rec + (size_t)(i + 2 - base) * REC_U;
            wuT = r[kk]; eaT = *(const float4*)(r + 64); srcT = ((const int*)r)[68];
        }
        float4 xsB = make_float4(0.f,0.f,0.f,0.f);
        if (i + 1 < end) xsB = h4[(size_t)srcB * 32 + c];

        float wA = bf_lo(wuA), wB = bf_hi(wuA);
        float4 ea = eaA, xs = xsA;
        if (half == 0) {
            acc0 = fmaf(wA * xs.x, ea.x, acc0);          // m0a
            float bx = wB * xs.x;
            acc1 = fmaf(bx, ea.y, acc1);                 // m1a
            acc2 = fmaf(bx, ea.z, acc2);
            acc3 = fmaf(bx, ea.w, acc3);
        } else {
            float dv = xs.y * ea.y + xs.z * ea.z + xs.w * ea.w;
            acc0 = fmaf(wB * SQ3_INVF, dv, acc0);        // m0b
            float cy = wA * ea.x;
            acc1 = fmaf(cy, xs.y, acc1);                 // m1b
            acc2 = fmaf(cy, xs.z, acc2);
            acc3 = fmaf(cy, xs.w, acc3);
        }
        wuA = wuB; eaA = eaB; srcA = srcB; xsA = xsB;
        wuB = wuT; eaB = eaT; srcB = srcT;
    }

    if (n < N) {
        if (half == 0) {
            ld[w][c] = acc0;
            ld[w][64 + c * 3 + 0] = acc1;
            ld[w][64 + c * 3 + 1] = acc2;
            ld[w][64 + c * 3 + 2] = acc3;
        } else {
            ld[w][32 + c] = acc0;
            ld[w][160 + c * 3 + 0] = acc1;
            ld[w][160 + c * 3 + 1] = acc2;
            ld[w][160 + c * 3 + 2] = acc3;
        }
    }
    __syncthreads();
    if (n < N && end > beg) {
        #pragma unroll
        for (int hh = 0; hh < 2; ++hh) {
            int j = t + hh * 64;
            float acc = 0.f;
            if (j < 32) {
                #pragma unroll
                for (int u = 0; u < 64; ++u) acc = fmaf(ld[w][u], l2w0[u * 32 + j], acc);
            } else {
                int jj = j - 32, vch = jj / 3, m = jj - vch * 3;
                #pragma unroll
                for (int u = 0; u < 64; ++u) acc = fmaf(ld[w][64 + u * 3 + m], l2w1[u * 32 + vch], acc);
            }
            out[(size_t)n * 128 + j] += acc * LIN2_SCALE;
        }
    }
}

// ---------------- FALLBACK (ws too small): round-2 fused gather ----------------
__global__ __launch_bounds__(64) void gather_kernel(
    const float* __restrict__ ee, const float4* __restrict__ eattr4,
    const int* __restrict__ eidx, const int* __restrict__ order,
    const int* __restrict__ off,
    const float* __restrict__ w0, const float2* __restrict__ w1p2,
    const float4* __restrict__ h4,
    const float* __restrict__ l2w0, const float* __restrict__ l2w1,
    float* __restrict__ out, int E) {
    int n = blockIdx.x, t = threadIdx.x;
    int beg = off[n], end = off[n + 1];
    __shared__ float s_ee[8];
    __shared__ float s_hid[64];
    __shared__ float ld[256];
    float acc0 = 0.f, acc1 = 0.f, acc2 = 0.f, acc3 = 0.f;
    int c = t & 31;
    for (int i = beg; i < end; ++i) {
        int e = order[i];
        int src = eidx[E + e];
        if (t < 8) s_ee[t] = ee[e * 8 + t] * SQRT8_INV;
        __syncthreads();
        float a = 0.f;
        #pragma unroll
        for (int k = 0; k < 8; ++k) a = fmaf(s_ee[k], w0[k * 64 + t], a);
        float sg = 1.f / (1.f + __expf(-a));
        __syncthreads();
        s_hid[t] = a * sg * W1_SCALE;
        __syncthreads();
        float wA = 0.f, wB = 0.f;
        #pragma unroll
        for (int j = 0; j < 64; ++j) {
            float2 wv = w1p2[j * 64 + t];
            float hj = s_hid[j];
            wA = fmaf(hj, wv.x, wA);
            wB = fmaf(hj, wv.y, wB);
        }
        float4 xs = h4[(size_t)src * 32 + c];
        float4 ea = eattr4[e];
        if (t < 32) {
            acc0 = fmaf(wA * xs.x, ea.x, acc0);
            float bx = wB * xs.x;
            acc1 = fmaf(bx, ea.y, acc1);
            acc2 = fmaf(bx, ea.z, acc2);
            acc3 = fmaf(bx, ea.w, acc3);
        } else {
            float dv = xs.y * ea.y + xs.z * ea.z + xs.w * ea.w;
            acc0 = fmaf(wB * SQ3_INVF, dv, acc0);
            float cy = wA * ea.x;
            acc1 = fmaf(cy, xs.y, acc1);
            acc2 = fmaf(cy, xs.z, acc2);
            acc3 = fmaf(cy, xs.w, acc3);
        }
    }
    if (t < 32) {
        ld[t] = acc0;
        ld[64 + t * 3 + 0] = acc1;
        ld[64 + t * 3 + 1] = acc2;
        ld[64 + t * 3 + 2] = acc3;
    } else {
        int cc = t - 32;
        ld[32 + cc] = acc0;
        ld[160 + cc * 3 + 0] = acc1;
        ld[160 + cc * 3 + 1] = acc2;
        ld[160 + cc * 3 + 2] = acc3;
    }
    __syncthreads();
    #pragma unroll
    for (int hh = 0; hh < 2; ++hh) {
        int j = t + hh * 64;
        float acc = 0.f;
        if (j < 32) {
            #pragma unroll
            for (int u = 0; u < 64; ++u) acc = fmaf(ld[u], l2w0[u * 32 + j], acc);
        } else {
            int jj = j - 32, vch = jj / 3, m = jj - vch * 3;
            #pragma unroll
            for (int u = 0; u < 64; ++u) acc = fmaf(ld[64 + u * 3 + m], l2w1[u * 32 + vch], acc);
        }
        out[(size_t)n * 128 + j] += acc * LIN2_SCALE;
    }
}

extern "C" void kernel_launch(void* const* d_in, const int* in_sizes, int n_in,
                              void* d_out, int out_size, void* d_ws, size_t ws_size,
                              hipStream_t stream) {
    const float* nf    = (const float*)d_in[0];
    const float* attrs = (const float*)d_in[1];
    const float* eattr = (const float*)d_in[2];
    const float* ee    = (const float*)d_in[3];
    const int*   eidx  = (const int*)d_in[4];
    const float* l1w0  = (const float*)d_in[5];
    const float* l1w1  = (const float*)d_in[6];
    const float* w0    = (const float*)d_in[7];
    const float* w1    = (const float*)d_in[8];
    const float* l2w0  = (const float*)d_in[9];
    const float* l2w1  = (const float*)d_in[10];
    const float* scw0  = (const float*)d_in[11];
    const float* scw1  = (const float*)d_in[12];

    int N = in_sizes[0] / 128;
    int E = in_sizes[3] / 8;

    // ws layout: h4 | w1x | w1p | cnt | off | cur | order | rec (segment buffer)
    float* h4    = (float*)d_ws;                       // N*128
    float* w1x   = h4 + (size_t)N * 128;               // 8192
    float* w1p   = w1x + 8192;                         // 8192
    int*   cnt   = (int*)(w1p + 8192);                 // N
    int*   off   = cnt + N;                            // N+1
    int*   cur   = off + N + 1;                        // N
    int*   order = cur + N;                            // E
    size_t rec_off = (((size_t)(order + E) - (size_t)d_ws) + 255) & ~(size_t)255;
    unsigned* rec = (unsigned*)((char*)d_ws + rec_off);

    int L0 = ((E / 2) + 255) / 256 * 256;
    if (L0 > E) L0 = E;
    int len0 = L0, len1 = E - L0;
    int maxlen = len0 > len1 ? len0 : len1;

    size_t need = rec_off + (size_t)maxlen * REC_B;
    bool big = ws_size >= need;

    zero_int<<<(N + 255) / 256, 256, 0, stream>>>(cnt, N);
    hist_kernel<<<(E + 255) / 256, 256, 0, stream>>>(eidx, cnt, E);
    scan_kernel<<<1, 1024, 0, stream>>>(cnt, off, cur, N);
    scatter_kernel<<<(E + 255) / 256, 256, 0, stream>>>(eidx, cur, order, E);
    node_kernel<<<N, 128, 0, stream>>>(nf, attrs, l1w0, l1w1, scw0, scw1, h4, (float*)d_out);

    if (big) {
        prep_w1x<<<32, 256, 0, stream>>>(w1, w1x);
        mlp_kernel<<<(len0 + 255) / 256, 256, 0, stream>>>(ee, (const float4*)eattr,
                                                           eidx, order, w0, w1x,
                                                           rec, 0, len0, E);
        reduce_kernel<<<(N + 3) / 4, 256, 0, stream>>>(rec, off, (const float4*)h4,
                                                       l2w0, l2w1, (float*)d_out,
                                                       N, 0, len0);
        if (len1 > 0) {
            mlp_kernel<<<(len1 + 255) / 256, 256, 0, stream>>>(ee, (const float4*)eattr,
                                                               eidx, order, w0, w1x,
                                                               rec, L0, len1, E);
            reduce_kernel<<<(N + 3) / 4, 256, 0, stream>>>(rec, off, (const float4*)h4,
                                                           l2w0, l2w1, (float*)d_out,
                                                           N, L0, len1);
        }
    } else {
        prep_w1p<<<16, 256, 0, stream>>>(w1, w1p);
        gather_kernel<<<N, 64, 0, stream>>>(ee, (const float4*)eattr, eidx, order, off,
                                            w0, (const float2*)w1p, (const float4*)h4,
                                            l2w0, l2w1, (float*)d_out, E);
    }
}

// Round 5
// 475.856 us; speedup vs baseline: 1.8629x; 1.5302x over previous
//
#include <hip/hip_runtime.h>
#include <math.h>

#define SQRT8_INV  0.35355339059327373f   // 1/sqrt(8)
#define H_SCALE    0.04419417382415922f   // 0.25/sqrt(32)
#define FAN_SC     0.04419417382415922f   // 1/sqrt(32*16)
#define W1_SCALE   0.125f                 // 1/sqrt(64)
#define LIN2_SCALE 0.125f                 // 1/sqrt(64)
#define SQ3_INVF   0.57735026918962576f   // 1/sqrt(3)

// record layout per sorted edge slot: 320 B = 80 uints
//   [0..63]  w-words: word j = pack_bf16(w[j], w[j+64]),  j = 0..63
//   [64..67] eattr float4
//   [68]     src node id
//   [69..79] pad
#define REC_U 80
#define REC_B 320

typedef __attribute__((ext_vector_type(8))) short short8;
typedef __attribute__((ext_vector_type(4))) float f32x4;

__device__ __forceinline__ unsigned pack_bf16(float a, float b) {
    unsigned ua = __float_as_uint(a);
    ua += 0x7FFFu + ((ua >> 16) & 1u);          // RNE
    unsigned ub = __float_as_uint(b);
    ub += 0x7FFFu + ((ub >> 16) & 1u);
    return (ua >> 16) | (ub & 0xFFFF0000u);
}
__device__ __forceinline__ short bf16b(float x) {
    unsigned u = __float_as_uint(x);
    u += 0x7FFFu + ((u >> 16) & 1u);
    return (short)(u >> 16);
}
__device__ __forceinline__ float bf_lo(unsigned u) { return __uint_as_float(u << 16); }
__device__ __forceinline__ float bf_hi(unsigned u) { return __uint_as_float(u & 0xFFFF0000u); }

// ---------------- zero int buffer ----------------
__global__ __launch_bounds__(256) void zero_int(int* __restrict__ p, int n) {
    int i = blockIdx.x * 256 + threadIdx.x;
    if (i < n) p[i] = 0;
}

// ---------------- w1 -> w1p (fallback gather path) ----------------
__global__ __launch_bounds__(256) void prep_w1p(const float* __restrict__ w1,
                                                float* __restrict__ w1p) {
    int idx = blockIdx.x * 256 + threadIdx.x;
    if (idx >= 64 * 64) return;
    int j = idx >> 6, t = idx & 63;
    int colA = (t < 32) ? t : t + 32;
    int colB = (t < 32) ? t + 32 : t + 64;
    w1p[idx * 2 + 0] = w1[j * 128 + colA];
    w1p[idx * 2 + 1] = w1[j * 128 + colB];
}

// ---------------- histogram of edge_dst ----------------
__global__ __launch_bounds__(256) void hist_kernel(const int* __restrict__ eidx,
                                                   int* __restrict__ cnt, int E) {
    int e = blockIdx.x * 256 + threadIdx.x;
    if (e < E) atomicAdd(&cnt[eidx[e]], 1);
}

// ---------------- exclusive scan of counts (single block) ----------------
__global__ __launch_bounds__(1024) void scan_kernel(const int* __restrict__ cnt,
                                                    int* __restrict__ off,
                                                    int* __restrict__ cur, int N) {
    __shared__ int sums[1024];
    int t = threadIdx.x;
    int chunk = (N + 1023) >> 10;
    int lo = t * chunk, hi = min(lo + chunk, N);
    int s = 0;
    for (int i = lo; i < hi; ++i) s += cnt[i];
    sums[t] = s;
    __syncthreads();
    for (int d = 1; d < 1024; d <<= 1) {
        int v = (t >= d) ? sums[t - d] : 0;
        __syncthreads();
        sums[t] += v;
        __syncthreads();
    }
    int base = (t == 0) ? 0 : sums[t - 1];
    for (int i = lo; i < hi; ++i) { off[i] = base; cur[i] = base; base += cnt[i]; }
    if (t == 1023) off[N] = sums[1023];
}

// ---------------- scatter edge ids into dst-sorted order ----------------
__global__ __launch_bounds__(256) void scatter_kernel(const int* __restrict__ eidx,
                                                      int* __restrict__ cur,
                                                      int* __restrict__ order, int E) {
    int e = blockIdx.x * 256 + threadIdx.x;
    if (e >= E) return;
    int pos = atomicAdd(&cur[eidx[e]], 1);
    order[pos] = e;
}

// ---------------- node stage: h (lin1, interleaved float4) + sc into out ----------------
__global__ __launch_bounds__(128) void node_kernel(
    const float* __restrict__ nf, const float* __restrict__ attrs,
    const float* __restrict__ l1w0, const float* __restrict__ l1w1,
    const float* __restrict__ scw0, const float* __restrict__ scw1,
    float* __restrict__ h4, float* __restrict__ out) {
    int n = blockIdx.x;
    int t = threadIdx.x;
    __shared__ float x[128];
    __shared__ int vs;
    x[t] = nf[n * 128 + t];
    if (t < 16) {
        if (attrs[n * 16 + t] > 0.5f) vs = t;   // one-hot: exactly one writer
    }
    __syncthreads();
    int v = vs;
    if (t < 32) {
        int w = t;
        float a = 0.f, b = 0.f;
        #pragma unroll
        for (int u = 0; u < 32; ++u) {
            float xv = x[u];
            a = fmaf(xv, l1w0[u * 32 + w], a);
            b = fmaf(xv, scw0[u * 512 + v * 32 + w], b);
        }
        h4[n * 128 + w * 4] = a * H_SCALE;
        out[n * 128 + w]    = b * FAN_SC;
    } else {
        int j = t - 32;                // 0..95
        int vch = j / 3, m = j - vch * 3;
        float a = 0.f, b = 0.f;
        #pragma unroll
        for (int u = 0; u < 32; ++u) {
            float xv = x[32 + u * 3 + m];
            a = fmaf(xv, l1w1[u * 32 + vch], a);
            b = fmaf(xv, scw1[u * 512 + v * 32 + vch], b);
        }
        h4[n * 128 + vch * 4 + 1 + m]   = a * H_SCALE;
        out[n * 128 + 32 + vch * 3 + m] = b * FAN_SC;
    }
}

// ---------------- edge MLP: layer1 VALU + layer2 MFMA, direct coalesced rec stores ----
// block = 256 threads = 4 waves, 256 edges. Wave w owns channel words j in
// [w*16, w*16+16): word j = pack(bf16(out[chan=j]), bf16(out[chan=j+64])).
__global__ __launch_bounds__(256) void mlp_kernel(
    const float* __restrict__ ee, const float4* __restrict__ eattr4,
    const int* __restrict__ eidx, const int* __restrict__ order,
    const float* __restrict__ w0, const float* __restrict__ w1,
    unsigned* __restrict__ rec, int base, int len, int E) {
    __shared__ unsigned amat[256 * 32];     // A-tile: [edge][64 bf16], XOR-swizzled
    int tid  = threadIdx.x;
    int lane = tid & 63, wid = tid >> 6;
    int m = lane & 15, q = lane >> 4;
    int idx  = blockIdx.x * 256 + tid;
    bool valid = idx < len;

    // ---- B fragments (once per block): bf16(w1[k][chan]), k-chunk q*8+i
    short8 bf00, bf01, bf10, bf11;          // [chan tile lo/hi][k-step 0/1]
    {
        int clo = wid * 16 + m, chi = clo + 64;
        #pragma unroll
        for (int i = 0; i < 8; ++i) {
            int k0 = q * 8 + i, k1 = 32 + q * 8 + i;
            bf00[i] = bf16b(w1[k0 * 128 + clo]);
            bf01[i] = bf16b(w1[k1 * 128 + clo]);
            bf10[i] = bf16b(w1[k0 * 128 + chi]);
            bf11[i] = bf16b(w1[k1 * 128 + chi]);
        }
    }

    // ---- layer 1 + silu (per-lane, weights uniform -> scalar loads)
    int src = 0;
    float4 ea = make_float4(0.f, 0.f, 0.f, 0.f);
    float hid[64];
    if (valid) {
        int e = order[base + idx];
        src = eidx[E + e];
        ea  = eattr4[e];
        const float4* eep = (const float4*)ee;
        float4 e0 = eep[(size_t)e * 2], e1 = eep[(size_t)e * 2 + 1];
        float eev[8];
        eev[0] = e0.x * SQRT8_INV; eev[1] = e0.y * SQRT8_INV;
        eev[2] = e0.z * SQRT8_INV; eev[3] = e0.w * SQRT8_INV;
        eev[4] = e1.x * SQRT8_INV; eev[5] = e1.y * SQRT8_INV;
        eev[6] = e1.z * SQRT8_INV; eev[7] = e1.w * SQRT8_INV;
        #pragma unroll
        for (int j = 0; j < 64; ++j) {
            float a = 0.f;
            #pragma unroll
            for (int k = 0; k < 8; ++k) a = fmaf(eev[k], w0[k * 64 + j], a);
            float s = 1.f / (1.f + __expf(-a));
            hid[j] = a * s * W1_SCALE;
        }
    } else {
        #pragma unroll
        for (int j = 0; j < 64; ++j) hid[j] = 0.f;
    }

    // ---- stage A (bf16, swizzled: byte_off ^= (row&7)<<4; row stride 128 B)
    {
        char* arow = (char*)(amat + tid * 32);
        #pragma unroll
        for (int kc = 0; kc < 8; ++kc) {
            uint4 v;
            v.x = pack_bf16(hid[kc * 8 + 0], hid[kc * 8 + 1]);
            v.y = pack_bf16(hid[kc * 8 + 2], hid[kc * 8 + 3]);
            v.z = pack_bf16(hid[kc * 8 + 4], hid[kc * 8 + 5]);
            v.w = pack_bf16(hid[kc * 8 + 6], hid[kc * 8 + 7]);
            *(uint4*)(arow + ((kc * 16) ^ ((tid & 7) << 4))) = v;
        }
    }
    __syncthreads();

    // ---- MFMA: 16 edge-tiles x (lo,hi chan tiles) x K=64
    int jb = wid * 16;
    int blockbase = blockIdx.x * 256;
    for (int et = 0; et < 16; ++et) {
        int row = et * 16 + m;
        const char* abase = (const char*)(amat + row * 32);
        int swz = (row & 7) << 4;
        short8 a0 = *(const short8*)(abase + ((q * 16) ^ swz));
        short8 a1 = *(const short8*)(abase + (((64 + q * 16)) ^ swz));
        f32x4 dlo = {0.f, 0.f, 0.f, 0.f}, dhi = {0.f, 0.f, 0.f, 0.f};
        dlo = __builtin_amdgcn_mfma_f32_16x16x32_bf16(a0, bf00, dlo, 0, 0, 0);
        dlo = __builtin_amdgcn_mfma_f32_16x16x32_bf16(a1, bf01, dlo, 0, 0, 0);
        dhi = __builtin_amdgcn_mfma_f32_16x16x32_bf16(a0, bf10, dhi, 0, 0, 0);
        dhi = __builtin_amdgcn_mfma_f32_16x16x32_bf16(a1, bf11, dhi, 0, 0, 0);
        // D: row(edge-within-tile) = 4*q + i, col(word) = jb + m
        #pragma unroll
        for (int i = 0; i < 4; ++i) {
            int eloc = blockbase + et * 16 + 4 * q + i;
            if (eloc < len)
                rec[(size_t)eloc * REC_U + jb + m] = pack_bf16(dlo[i], dhi[i]);
        }
    }

    // ---- tail fields
    if (valid) {
        unsigned* myrec = rec + (size_t)idx * REC_U;
        *(float4*)(myrec + 64) = ea;
        ((int*)myrec)[68] = src;
    }
}

// ---------------- reduce: sequential record stream + h4 gather, fused lin2 ----------------
__global__ __launch_bounds__(256) void reduce_kernel(
    const unsigned* __restrict__ rec, const int* __restrict__ off,
    const float4* __restrict__ h4,
    const float* __restrict__ l2w0, const float* __restrict__ l2w1,
    float* __restrict__ out, int N, int base, int len) {
    int w = threadIdx.x >> 6, t = threadIdx.x & 63;
    int n = blockIdx.x * 4 + w;
    __shared__ float ld[4][256];
    int c = t & 31;
    int half = t >> 5;
    int kk = half ? (c + 32) : c;       // word index this thread consumes
    float acc0 = 0.f, acc1 = 0.f, acc2 = 0.f, acc3 = 0.f;

    int beg = 0, end = 0;
    if (n < N) {
        beg = max(off[n], base);
        end = min(off[n + 1], base + len);
    }

    // software pipeline: depth-2 record fields, depth-1 h4 gather
    unsigned wuA = 0, wuB = 0;
    float4 eaA = make_float4(0.f,0.f,0.f,0.f), eaB = eaA;
    int srcA = 0, srcB = 0;
    float4 xsA = make_float4(0.f,0.f,0.f,0.f);
    if (beg < end) {
        const unsigned* r = rec + (size_t)(beg - base) * REC_U;
        wuA = r[kk]; eaA = *(const float4*)(r + 64); srcA = ((const int*)r)[68];
        xsA = h4[(size_t)srcA * 32 + c];
        if (beg + 1 < end) {
            const unsigned* r1 = rec + (size_t)(beg + 1 - base) * REC_U;
            wuB = r1[kk]; eaB = *(const float4*)(r1 + 64); srcB = ((const int*)r1)[68];
        }
    }
    for (int i = beg; i < end; ++i) {
        unsigned wuT = 0; float4 eaT = make_float4(0.f,0.f,0.f,0.f); int srcT = 0;
        if (i + 2 < end) {
            const unsigned* r = rec + (size_t)(i + 2 - base) * REC_U;
            wuT = r[kk]; eaT = *(const float4*)(r + 64); srcT = ((const int*)r)[68];
        }
        float4 xsB = make_float4(0.f,0.f,0.f,0.f);
        if (i + 1 < end) xsB = h4[(size_t)srcB * 32 + c];

        float wlo = bf_lo(wuA), whi = bf_hi(wuA);
        float4 ea = eaA, xs = xsA;
        if (half == 0) {
            // wlo = wa = w[c], whi = wc = w[c+64]
            acc0 = fmaf(wlo * xs.x, ea.x, acc0);         // m0a
            float cy = whi * ea.x;
            acc1 = fmaf(cy, xs.y, acc1);                 // m1b
            acc2 = fmaf(cy, xs.z, acc2);
            acc3 = fmaf(cy, xs.w, acc3);
        } else {
            // wlo = wb = w[c+32], whi = wd = w[c+96]
            float bx = wlo * xs.x;
            acc1 = fmaf(bx, ea.y, acc1);                 // m1a
            acc2 = fmaf(bx, ea.z, acc2);
            acc3 = fmaf(bx, ea.w, acc3);
            float dv = xs.y * ea.y + xs.z * ea.z + xs.w * ea.w;
            acc0 = fmaf(whi * SQ3_INVF, dv, acc0);       // m0b
        }
        wuA = wuB; eaA = eaB; srcA = srcB; xsA = xsB;
        wuB = wuT; eaB = eaT; srcB = srcT;
    }

    if (n < N) {
        if (half == 0) {
            ld[w][c] = acc0;                             // m0a
            ld[w][160 + c * 3 + 0] = acc1;               // m1b
            ld[w][160 + c * 3 + 1] = acc2;
            ld[w][160 + c * 3 + 2] = acc3;
        } else {
            ld[w][32 + c] = acc0;                        // m0b
            ld[w][64 + c * 3 + 0] = acc1;                // m1a
            ld[w][64 + c * 3 + 1] = acc2;
            ld[w][64 + c * 3 + 2] = acc3;
        }
    }
    __syncthreads();
    if (n < N && end > beg) {
        #pragma unroll
        for (int hh = 0; hh < 2; ++hh) {
            int j = t + hh * 64;
            float acc = 0.f;
            if (j < 32) {
                #pragma unroll
                for (int u = 0; u < 64; ++u) acc = fmaf(ld[w][u], l2w0[u * 32 + j], acc);
            } else {
                int jj = j - 32, vch = jj / 3, m = jj - vch * 3;
                #pragma unroll
                for (int u = 0; u < 64; ++u) acc = fmaf(ld[w][64 + u * 3 + m], l2w1[u * 32 + vch], acc);
            }
            out[(size_t)n * 128 + j] += acc * LIN2_SCALE;
        }
    }
}

// ---------------- FALLBACK (ws too small): round-2 fused gather ----------------
__global__ __launch_bounds__(64) void gather_kernel(
    const float* __restrict__ ee, const float4* __restrict__ eattr4,
    const int* __restrict__ eidx, const int* __restrict__ order,
    const int* __restrict__ off,
    const float* __restrict__ w0, const float2* __restrict__ w1p2,
    const float4* __restrict__ h4,
    const float* __restrict__ l2w0, const float* __restrict__ l2w1,
    float* __restrict__ out, int E) {
    int n = blockIdx.x, t = threadIdx.x;
    int beg = off[n], end = off[n + 1];
    __shared__ float s_ee[8];
    __shared__ float s_hid[64];
    __shared__ float ld[256];
    float acc0 = 0.f, acc1 = 0.f, acc2 = 0.f, acc3 = 0.f;
    int c = t & 31;
    for (int i = beg; i < end; ++i) {
        int e = order[i];
        int src = eidx[E + e];
        if (t < 8) s_ee[t] = ee[e * 8 + t] * SQRT8_INV;
        __syncthreads();
        float a = 0.f;
        #pragma unroll
        for (int k = 0; k < 8; ++k) a = fmaf(s_ee[k], w0[k * 64 + t], a);
        float sg = 1.f / (1.f + __expf(-a));
        __syncthreads();
        s_hid[t] = a * sg * W1_SCALE;
        __syncthreads();
        float wA = 0.f, wB = 0.f;
        #pragma unroll
        for (int j = 0; j < 64; ++j) {
            float2 wv = w1p2[j * 64 + t];
            float hj = s_hid[j];
            wA = fmaf(hj, wv.x, wA);
            wB = fmaf(hj, wv.y, wB);
        }
        float4 xs = h4[(size_t)src * 32 + c];
        float4 ea = eattr4[e];
        if (t < 32) {
            acc0 = fmaf(wA * xs.x, ea.x, acc0);
            float bx = wB * xs.x;
            acc1 = fmaf(bx, ea.y, acc1);
            acc2 = fmaf(bx, ea.z, acc2);
            acc3 = fmaf(bx, ea.w, acc3);
        } else {
            float dv = xs.y * ea.y + xs.z * ea.z + xs.w * ea.w;
            acc0 = fmaf(wB * SQ3_INVF, dv, acc0);
            float cy = wA * ea.x;
            acc1 = fmaf(cy, xs.y, acc1);
            acc2 = fmaf(cy, xs.z, acc2);
            acc3 = fmaf(cy, xs.w, acc3);
        }
    }
    if (t < 32) {
        ld[t] = acc0;
        ld[64 + t * 3 + 0] = acc1;
        ld[64 + t * 3 + 1] = acc2;
        ld[64 + t * 3 + 2] = acc3;
    } else {
        int cc = t - 32;
        ld[32 + cc] = acc0;
        ld[160 + cc * 3 + 0] = acc1;
        ld[160 + cc * 3 + 1] = acc2;
        ld[160 + cc * 3 + 2] = acc3;
    }
    __syncthreads();
    #pragma unroll
    for (int hh = 0; hh < 2; ++hh) {
        int j = t + hh * 64;
        float acc = 0.f;
        if (j < 32) {
            #pragma unroll
            for (int u = 0; u < 64; ++u) acc = fmaf(ld[u], l2w0[u * 32 + j], acc);
        } else {
            int jj = j - 32, vch = jj / 3, m = jj - vch * 3;
            #pragma unroll
            for (int u = 0; u < 64; ++u) acc = fmaf(ld[64 + u * 3 + m], l2w1[u * 32 + vch], acc);
        }
        out[(size_t)n * 128 + j] += acc * LIN2_SCALE;
    }
}

extern "C" void kernel_launch(void* const* d_in, const int* in_sizes, int n_in,
                              void* d_out, int out_size, void* d_ws, size_t ws_size,
                              hipStream_t stream) {
    const float* nf    = (const float*)d_in[0];
    const float* attrs = (const float*)d_in[1];
    const float* eattr = (const float*)d_in[2];
    const float* ee    = (const float*)d_in[3];
    const int*   eidx  = (const int*)d_in[4];
    const float* l1w0  = (const float*)d_in[5];
    const float* l1w1  = (const float*)d_in[6];
    const float* w0    = (const float*)d_in[7];
    const float* w1    = (const float*)d_in[8];
    const float* l2w0  = (const float*)d_in[9];
    const float* l2w1  = (const float*)d_in[10];
    const float* scw0  = (const float*)d_in[11];
    const float* scw1  = (const float*)d_in[12];

    int N = in_sizes[0] / 128;
    int E = in_sizes[3] / 8;

    // ws layout: h4 | w1p | cnt | off | cur | order | rec (segment buffer)
    float* h4    = (float*)d_ws;                       // N*128
    float* w1p   = h4 + (size_t)N * 128;               // 8192
    int*   cnt   = (int*)(w1p + 8192);                 // N
    int*   off   = cnt + N;                            // N+1
    int*   cur   = off + N + 1;                        // N
    int*   order = cur + N;                            // E
    size_t rec_off = (((size_t)(order + E) - (size_t)d_ws) + 255) & ~(size_t)255;
    unsigned* rec = (unsigned*)((char*)d_ws + rec_off);

    int L0 = ((E / 2) + 255) / 256 * 256;
    if (L0 > E) L0 = E;
    int len0 = L0, len1 = E - L0;
    int maxlen = len0 > len1 ? len0 : len1;

    size_t need = rec_off + (size_t)maxlen * REC_B;
    bool big = ws_size >= need;

    zero_int<<<(N + 255) / 256, 256, 0, stream>>>(cnt, N);
    hist_kernel<<<(E + 255) / 256, 256, 0, stream>>>(eidx, cnt, E);
    scan_kernel<<<1, 1024, 0, stream>>>(cnt, off, cur, N);
    scatter_kernel<<<(E + 255) / 256, 256, 0, stream>>>(eidx, cur, order, E);
    node_kernel<<<N, 128, 0, stream>>>(nf, attrs, l1w0, l1w1, scw0, scw1, h4, (float*)d_out);

    if (big) {
        mlp_kernel<<<(len0 + 255) / 256, 256, 0, stream>>>(ee, (const float4*)eattr,
                                                           eidx, order, w0, w1,
                                                           rec, 0, len0, E);
        reduce_kernel<<<(N + 3) / 4, 256, 0, stream>>>(rec, off, (const float4*)h4,
                                                       l2w0, l2w1, (float*)d_out,
                                                       N, 0, len0);
        if (len1 > 0) {
            mlp_kernel<<<(len1 + 255) / 256, 256, 0, stream>>>(ee, (const float4*)eattr,
                                                               eidx, order, w0, w1,
                                                               rec, L0, len1, E);
            reduce_kernel<<<(N + 3) / 4, 256, 0, stream>>>(rec, off, (const float4*)h4,
                                                           l2w0, l2w1, (float*)d_out,
                                                           N, L0, len1);
        }
    } else {
        prep_w1p<<<16, 256, 0, stream>>>(w1, w1p);
        gather_kernel<<<N, 64, 0, stream>>>(ee, (const float4*)eattr, eidx, order, off,
                                            w0, (const float2*)w1p, (const float4*)h4,
                                            l2w0, l2w1, (float*)d_out, E);
    }
}

// Round 6
// 398.594 us; speedup vs baseline: 2.2240x; 1.1938x over previous
//
#include <hip/hip_runtime.h>
#include <math.h>

#define SQRT8_INV  0.35355339059327373f   // 1/sqrt(8)
#define H_SCALE    0.04419417382415922f   // 0.25/sqrt(32)
#define FAN_SC     0.04419417382415922f   // 1/sqrt(32*16)
#define W1_SCALE   0.125f                 // 1/sqrt(64)
#define LIN2_SCALE 0.125f                 // 1/sqrt(64)
#define SQ3_INVF   0.57735026918962576f   // 1/sqrt(3)

// record layout per sorted edge slot: 320 B = 80 uints
//   [0..63]  w-words: word j = pack_bf16(w[j], w[j+64]),  j = 0..63
//   [64..67] eattr float4
//   [68]     src node id
//   [69..79] pad
#define REC_U 80
#define REC_B 320

typedef __attribute__((ext_vector_type(8))) short short8;
typedef __attribute__((ext_vector_type(4))) float f32x4;

__device__ __forceinline__ unsigned pack_bf16(float a, float b) {
    unsigned ua = __float_as_uint(a);
    ua += 0x7FFFu + ((ua >> 16) & 1u);          // RNE
    unsigned ub = __float_as_uint(b);
    ub += 0x7FFFu + ((ub >> 16) & 1u);
    return (ua >> 16) | (ub & 0xFFFF0000u);
}
__device__ __forceinline__ short bf16b(float x) {
    unsigned u = __float_as_uint(x);
    u += 0x7FFFu + ((u >> 16) & 1u);
    return (short)(u >> 16);
}
__device__ __forceinline__ float bf_lo(unsigned u) { return __uint_as_float(u << 16); }
__device__ __forceinline__ float bf_hi(unsigned u) { return __uint_as_float(u & 0xFFFF0000u); }

// ---------------- zero int buffer ----------------
__global__ __launch_bounds__(256) void zero_int(int* __restrict__ p, int n) {
    int i = blockIdx.x * 256 + threadIdx.x;
    if (i < n) p[i] = 0;
}

// ---------------- w1 -> w1p (fallback gather path) ----------------
__global__ __launch_bounds__(256) void prep_w1p(const float* __restrict__ w1,
                                                float* __restrict__ w1p) {
    int idx = blockIdx.x * 256 + threadIdx.x;
    if (idx >= 64 * 64) return;
    int j = idx >> 6, t = idx & 63;
    int colA = (t < 32) ? t : t + 32;
    int colB = (t < 32) ? t + 32 : t + 64;
    w1p[idx * 2 + 0] = w1[j * 128 + colA];
    w1p[idx * 2 + 1] = w1[j * 128 + colB];
}

// ---------------- histogram of edge_dst ----------------
__global__ __launch_bounds__(256) void hist_kernel(const int* __restrict__ eidx,
                                                   int* __restrict__ cnt, int E) {
    int e = blockIdx.x * 256 + threadIdx.x;
    if (e < E) atomicAdd(&cnt[eidx[e]], 1);
}

// ---------------- hierarchical scan, stage A: per-block sums ----------------
__global__ __launch_bounds__(256) void scan_bsum(const int* __restrict__ cnt,
                                                 int* __restrict__ bsum, int N) {
    __shared__ int red[256];
    int t = threadIdx.x, i = blockIdx.x * 256 + t;
    red[t] = (i < N) ? cnt[i] : 0;
    __syncthreads();
    #pragma unroll
    for (int d = 128; d > 0; d >>= 1) {
        if (t < d) red[t] += red[t + d];
        __syncthreads();
    }
    if (t == 0) bsum[blockIdx.x] = red[0];
}

// ---------------- stage B: exclusive scan of block sums (nb <= 1024) ----------------
__global__ __launch_bounds__(1024) void scan_bscan(int* __restrict__ bsum, int nb) {
    __shared__ int s[1024];
    int t = threadIdx.x;
    int v = (t < nb) ? bsum[t] : 0;
    s[t] = v;
    __syncthreads();
    for (int d = 1; d < 1024; d <<= 1) {
        int u = (t >= d) ? s[t - d] : 0;
        __syncthreads();
        s[t] += u;
        __syncthreads();
    }
    if (t < nb) bsum[t] = s[t] - v;   // exclusive
}

// ---------------- stage C: in-block scan + base -> off, cur ----------------
__global__ __launch_bounds__(256) void scan_final(const int* __restrict__ cnt,
                                                  const int* __restrict__ bsum,
                                                  int* __restrict__ off,
                                                  int* __restrict__ cur, int N) {
    __shared__ int s[256];
    int t = threadIdx.x, i = blockIdx.x * 256 + t;
    int v = (i < N) ? cnt[i] : 0;
    s[t] = v;
    __syncthreads();
    for (int d = 1; d < 256; d <<= 1) {
        int u = (t >= d) ? s[t - d] : 0;
        __syncthreads();
        s[t] += u;
        __syncthreads();
    }
    int ex = s[t] - v + bsum[blockIdx.x];
    if (i < N) { off[i] = ex; cur[i] = ex; }
    if (i == N - 1) off[N] = ex + v;
}

// ---------------- scatter edge ids into dst-sorted order ----------------
__global__ __launch_bounds__(256) void scatter_kernel(const int* __restrict__ eidx,
                                                      int* __restrict__ cur,
                                                      int* __restrict__ order, int E) {
    int e = blockIdx.x * 256 + threadIdx.x;
    if (e >= E) return;
    int pos = atomicAdd(&cur[eidx[e]], 1);
    order[pos] = e;
}

// ---------------- node stage: h (lin1, interleaved float4) + sc into out ----------------
__global__ __launch_bounds__(128) void node_kernel(
    const float* __restrict__ nf, const float* __restrict__ attrs,
    const float* __restrict__ l1w0, const float* __restrict__ l1w1,
    const float* __restrict__ scw0, const float* __restrict__ scw1,
    float* __restrict__ h4, float* __restrict__ out) {
    int n = blockIdx.x;
    int t = threadIdx.x;
    __shared__ float x[128];
    __shared__ int vs;
    x[t] = nf[n * 128 + t];
    if (t < 16) {
        if (attrs[n * 16 + t] > 0.5f) vs = t;   // one-hot: exactly one writer
    }
    __syncthreads();
    int v = vs;
    if (t < 32) {
        int w = t;
        float a = 0.f, b = 0.f;
        #pragma unroll
        for (int u = 0; u < 32; ++u) {
            float xv = x[u];
            a = fmaf(xv, l1w0[u * 32 + w], a);
            b = fmaf(xv, scw0[u * 512 + v * 32 + w], b);
        }
        h4[n * 128 + w * 4] = a * H_SCALE;
        out[n * 128 + w]    = b * FAN_SC;
    } else {
        int j = t - 32;                // 0..95
        int vch = j / 3, m = j - vch * 3;
        float a = 0.f, b = 0.f;
        #pragma unroll
        for (int u = 0; u < 32; ++u) {
            float xv = x[32 + u * 3 + m];
            a = fmaf(xv, l1w1[u * 32 + vch], a);
            b = fmaf(xv, scw1[u * 512 + v * 32 + vch], b);
        }
        h4[n * 128 + vch * 4 + 1 + m]   = a * H_SCALE;
        out[n * 128 + 32 + vch * 3 + m] = b * FAN_SC;
    }
}

// ---------------- edge MLP: layer1 VALU + layer2 MFMA, direct coalesced rec stores ----
__global__ __launch_bounds__(256) void mlp_kernel(
    const float* __restrict__ ee, const float4* __restrict__ eattr4,
    const int* __restrict__ eidx, const int* __restrict__ order,
    const float* __restrict__ w0, const float* __restrict__ w1,
    unsigned* __restrict__ rec, int base, int len, int E) {
    __shared__ unsigned amat[256 * 32];     // A-tile: [edge][64 bf16], XOR-swizzled
    int tid  = threadIdx.x;
    int lane = tid & 63, wid = tid >> 6;
    int m = lane & 15, q = lane >> 4;
    int idx  = blockIdx.x * 256 + tid;
    bool valid = idx < len;

    // ---- B fragments (once per block): bf16(w1[k][chan]), k-chunk q*8+i
    short8 bf00, bf01, bf10, bf11;          // [chan tile lo/hi][k-step 0/1]
    {
        int clo = wid * 16 + m, chi = clo + 64;
        #pragma unroll
        for (int i = 0; i < 8; ++i) {
            int k0 = q * 8 + i, k1 = 32 + q * 8 + i;
            bf00[i] = bf16b(w1[k0 * 128 + clo]);
            bf01[i] = bf16b(w1[k1 * 128 + clo]);
            bf10[i] = bf16b(w1[k0 * 128 + chi]);
            bf11[i] = bf16b(w1[k1 * 128 + chi]);
        }
    }

    // ---- layer 1 + silu (per-lane, weights uniform -> scalar loads)
    int src = 0;
    float4 ea = make_float4(0.f, 0.f, 0.f, 0.f);
    float hid[64];
    if (valid) {
        int e = order[base + idx];
        src = eidx[E + e];
        ea  = eattr4[e];
        const float4* eep = (const float4*)ee;
        float4 e0 = eep[(size_t)e * 2], e1 = eep[(size_t)e * 2 + 1];
        float eev[8];
        eev[0] = e0.x * SQRT8_INV; eev[1] = e0.y * SQRT8_INV;
        eev[2] = e0.z * SQRT8_INV; eev[3] = e0.w * SQRT8_INV;
        eev[4] = e1.x * SQRT8_INV; eev[5] = e1.y * SQRT8_INV;
        eev[6] = e1.z * SQRT8_INV; eev[7] = e1.w * SQRT8_INV;
        #pragma unroll
        for (int j = 0; j < 64; ++j) {
            float a = 0.f;
            #pragma unroll
            for (int k = 0; k < 8; ++k) a = fmaf(eev[k], w0[k * 64 + j], a);
            float s = 1.f / (1.f + __expf(-a));
            hid[j] = a * s * W1_SCALE;
        }
    } else {
        #pragma unroll
        for (int j = 0; j < 64; ++j) hid[j] = 0.f;
    }

    // ---- stage A (bf16, swizzled: byte_off ^= (row&7)<<4; row stride 128 B)
    {
        char* arow = (char*)(amat + tid * 32);
        #pragma unroll
        for (int kc = 0; kc < 8; ++kc) {
            uint4 v;
            v.x = pack_bf16(hid[kc * 8 + 0], hid[kc * 8 + 1]);
            v.y = pack_bf16(hid[kc * 8 + 2], hid[kc * 8 + 3]);
            v.z = pack_bf16(hid[kc * 8 + 4], hid[kc * 8 + 5]);
            v.w = pack_bf16(hid[kc * 8 + 6], hid[kc * 8 + 7]);
            *(uint4*)(arow + ((kc * 16) ^ ((tid & 7) << 4))) = v;
        }
    }
    __syncthreads();

    // ---- MFMA: 16 edge-tiles x (lo,hi chan tiles) x K=64
    int jb = wid * 16;
    int blockbase = blockIdx.x * 256;
    for (int et = 0; et < 16; ++et) {
        int row = et * 16 + m;
        const char* abase = (const char*)(amat + row * 32);
        int swz = (row & 7) << 4;
        short8 a0 = *(const short8*)(abase + ((q * 16) ^ swz));
        short8 a1 = *(const short8*)(abase + (((64 + q * 16)) ^ swz));
        f32x4 dlo = {0.f, 0.f, 0.f, 0.f}, dhi = {0.f, 0.f, 0.f, 0.f};
        dlo = __builtin_amdgcn_mfma_f32_16x16x32_bf16(a0, bf00, dlo, 0, 0, 0);
        dlo = __builtin_amdgcn_mfma_f32_16x16x32_bf16(a1, bf01, dlo, 0, 0, 0);
        dhi = __builtin_amdgcn_mfma_f32_16x16x32_bf16(a0, bf10, dhi, 0, 0, 0);
        dhi = __builtin_amdgcn_mfma_f32_16x16x32_bf16(a1, bf11, dhi, 0, 0, 0);
        // D: row(edge-within-tile) = 4*q + i, col(word) = jb + m
        #pragma unroll
        for (int i = 0; i < 4; ++i) {
            int eloc = blockbase + et * 16 + 4 * q + i;
            if (eloc < len)
                rec[(size_t)eloc * REC_U + jb + m] = pack_bf16(dlo[i], dhi[i]);
        }
    }

    // ---- tail fields
    if (valid) {
        unsigned* myrec = rec + (size_t)idx * REC_U;
        *(float4*)(myrec + 64) = ea;
        ((int*)myrec)[68] = src;
    }
}

// ---------------- reduce: sequential record stream + h4 gather, fused lin2 ----------------
__global__ __launch_bounds__(256) void reduce_kernel(
    const unsigned* __restrict__ rec, const int* __restrict__ off,
    const float4* __restrict__ h4,
    const float* __restrict__ l2w0, const float* __restrict__ l2w1,
    float* __restrict__ out, int N, int base, int len) {
    int w = threadIdx.x >> 6, t = threadIdx.x & 63;
    int n = blockIdx.x * 4 + w;
    __shared__ float ld[4][256];
    int c = t & 31;
    int half = t >> 5;
    int kk = half ? (c + 32) : c;       // word index this thread consumes
    float acc0 = 0.f, acc1 = 0.f, acc2 = 0.f, acc3 = 0.f;

    int beg = 0, end = 0;
    if (n < N) {
        beg = max(off[n], base);
        end = min(off[n + 1], base + len);
    }

    // software pipeline: depth-2 record fields, depth-1 h4 gather
    unsigned wuA = 0, wuB = 0;
    float4 eaA = make_float4(0.f,0.f,0.f,0.f), eaB = eaA;
    int srcA = 0, srcB = 0;
    float4 xsA = make_float4(0.f,0.f,0.f,0.f);
    if (beg < end) {
        const unsigned* r = rec + (size_t)(beg - base) * REC_U;
        wuA = r[kk]; eaA = *(const float4*)(r + 64); srcA = ((const int*)r)[68];
        xsA = h4[(size_t)srcA * 32 + c];
        if (beg + 1 < end) {
            const unsigned* r1 = rec + (size_t)(beg + 1 - base) * REC_U;
            wuB = r1[kk]; eaB = *(const float4*)(r1 + 64); srcB = ((const int*)r1)[68];
        }
    }
    for (int i = beg; i < end; ++i) {
        unsigned wuT = 0; float4 eaT = make_float4(0.f,0.f,0.f,0.f); int srcT = 0;
        if (i + 2 < end) {
            const unsigned* r = rec + (size_t)(i + 2 - base) * REC_U;
            wuT = r[kk]; eaT = *(const float4*)(r + 64); srcT = ((const int*)r)[68];
        }
        float4 xsB = make_float4(0.f,0.f,0.f,0.f);
        if (i + 1 < end) xsB = h4[(size_t)srcB * 32 + c];

        float wlo = bf_lo(wuA), whi = bf_hi(wuA);
        float4 ea = eaA, xs = xsA;
        if (half == 0) {
            // wlo = wa = w[c], whi = wc = w[c+64]
            acc0 = fmaf(wlo * xs.x, ea.x, acc0);         // m0a
            float cy = whi * ea.x;
            acc1 = fmaf(cy, xs.y, acc1);                 // m1b
            acc2 = fmaf(cy, xs.z, acc2);
            acc3 = fmaf(cy, xs.w, acc3);
        } else {
            // wlo = wb = w[c+32], whi = wd = w[c+96]
            float bx = wlo * xs.x;
            acc1 = fmaf(bx, ea.y, acc1);                 // m1a
            acc2 = fmaf(bx, ea.z, acc2);
            acc3 = fmaf(bx, ea.w, acc3);
            float dv = xs.y * ea.y + xs.z * ea.z + xs.w * ea.w;
            acc0 = fmaf(whi * SQ3_INVF, dv, acc0);       // m0b
        }
        wuA = wuB; eaA = eaB; srcA = srcB; xsA = xsB;
        wuB = wuT; eaB = eaT; srcB = srcT;
    }

    if (n < N) {
        if (half == 0) {
            ld[w][c] = acc0;                             // m0a
            ld[w][160 + c * 3 + 0] = acc1;               // m1b
            ld[w][160 + c * 3 + 1] = acc2;
            ld[w][160 + c * 3 + 2] = acc3;
        } else {
            ld[w][32 + c] = acc0;                        // m0b
            ld[w][64 + c * 3 + 0] = acc1;                // m1a
            ld[w][64 + c * 3 + 1] = acc2;
            ld[w][64 + c * 3 + 2] = acc3;
        }
    }
    __syncthreads();
    if (n < N && end > beg) {
        #pragma unroll
        for (int hh = 0; hh < 2; ++hh) {
            int j = t + hh * 64;
            float acc = 0.f;
            if (j < 32) {
                #pragma unroll
                for (int u = 0; u < 64; ++u) acc = fmaf(ld[w][u], l2w0[u * 32 + j], acc);
            } else {
                int jj = j - 32, vch = jj / 3, m = jj - vch * 3;
                #pragma unroll
                for (int u = 0; u < 64; ++u) acc = fmaf(ld[w][64 + u * 3 + m], l2w1[u * 32 + vch], acc);
            }
            out[(size_t)n * 128 + j] += acc * LIN2_SCALE;
        }
    }
}

// ---------------- FALLBACK (ws too small): round-2 fused gather ----------------
__global__ __launch_bounds__(64) void gather_kernel(
    const float* __restrict__ ee, const float4* __restrict__ eattr4,
    const int* __restrict__ eidx, const int* __restrict__ order,
    const int* __restrict__ off,
    const float* __restrict__ w0, const float2* __restrict__ w1p2,
    const float4* __restrict__ h4,
    const float* __restrict__ l2w0, const float* __restrict__ l2w1,
    float* __restrict__ out, int E) {
    int n = blockIdx.x, t = threadIdx.x;
    int beg = off[n], end = off[n + 1];
    __shared__ float s_ee[8];
    __shared__ float s_hid[64];
    __shared__ float ld[256];
    float acc0 = 0.f, acc1 = 0.f, acc2 = 0.f, acc3 = 0.f;
    int c = t & 31;
    for (int i = beg; i < end; ++i) {
        int e = order[i];
        int src = eidx[E + e];
        if (t < 8) s_ee[t] = ee[e * 8 + t] * SQRT8_INV;
        __syncthreads();
        float a = 0.f;
        #pragma unroll
        for (int k = 0; k < 8; ++k) a = fmaf(s_ee[k], w0[k * 64 + t], a);
        float sg = 1.f / (1.f + __expf(-a));
        __syncthreads();
        s_hid[t] = a * sg * W1_SCALE;
        __syncthreads();
        float wA = 0.f, wB = 0.f;
        #pragma unroll
        for (int j = 0; j < 64; ++j) {
            float2 wv = w1p2[j * 64 + t];
            float hj = s_hid[j];
            wA = fmaf(hj, wv.x, wA);
            wB = fmaf(hj, wv.y, wB);
        }
        float4 xs = h4[(size_t)src * 32 + c];
        float4 ea = eattr4[e];
        if (t < 32) {
            acc0 = fmaf(wA * xs.x, ea.x, acc0);
            float bx = wB * xs.x;
            acc1 = fmaf(bx, ea.y, acc1);
            acc2 = fmaf(bx, ea.z, acc2);
            acc3 = fmaf(bx, ea.w, acc3);
        } else {
            float dv = xs.y * ea.y + xs.z * ea.z + xs.w * ea.w;
            acc0 = fmaf(wB * SQ3_INVF, dv, acc0);
            float cy = wA * ea.x;
            acc1 = fmaf(cy, xs.y, acc1);
            acc2 = fmaf(cy, xs.z, acc2);
            acc3 = fmaf(cy, xs.w, acc3);
        }
    }
    if (t < 32) {
        ld[t] = acc0;
        ld[64 + t * 3 + 0] = acc1;
        ld[64 + t * 3 + 1] = acc2;
        ld[64 + t * 3 + 2] = acc3;
    } else {
        int cc = t - 32;
        ld[32 + cc] = acc0;
        ld[160 + cc * 3 + 0] = acc1;
        ld[160 + cc * 3 + 1] = acc2;
        ld[160 + cc * 3 + 2] = acc3;
    }
    __syncthreads();
    #pragma unroll
    for (int hh = 0; hh < 2; ++hh) {
        int j = t + hh * 64;
        float acc = 0.f;
        if (j < 32) {
            #pragma unroll
            for (int u = 0; u < 64; ++u) acc = fmaf(ld[u], l2w0[u * 32 + j], acc);
        } else {
            int jj = j - 32, vch = jj / 3, m = jj - vch * 3;
            #pragma unroll
            for (int u = 0; u < 64; ++u) acc = fmaf(ld[64 + u * 3 + m], l2w1[u * 32 + vch], acc);
        }
        out[(size_t)n * 128 + j] += acc * LIN2_SCALE;
    }
}

extern "C" void kernel_launch(void* const* d_in, const int* in_sizes, int n_in,
                              void* d_out, int out_size, void* d_ws, size_t ws_size,
                              hipStream_t stream) {
    const float* nf    = (const float*)d_in[0];
    const float* attrs = (const float*)d_in[1];
    const float* eattr = (const float*)d_in[2];
    const float* ee    = (const float*)d_in[3];
    const int*   eidx  = (const int*)d_in[4];
    const float* l1w0  = (const float*)d_in[5];
    const float* l1w1  = (const float*)d_in[6];
    const float* w0    = (const float*)d_in[7];
    const float* w1    = (const float*)d_in[8];
    const float* l2w0  = (const float*)d_in[9];
    const float* l2w1  = (const float*)d_in[10];
    const float* scw0  = (const float*)d_in[11];
    const float* scw1  = (const float*)d_in[12];

    int N = in_sizes[0] / 128;
    int E = in_sizes[3] / 8;
    int nb = (N + 255) / 256;

    // ws layout: h4 | w1p | cnt | off | cur | bsum | order | rec (segment buffer)
    float* h4    = (float*)d_ws;                       // N*128
    float* w1p   = h4 + (size_t)N * 128;               // 8192
    int*   cnt   = (int*)(w1p + 8192);                 // N
    int*   off   = cnt + N;                            // N+1
    int*   cur   = off + N + 1;                        // N
    int*   bsum  = cur + N;                            // nb
    int*   order = bsum + nb;                          // E
    size_t rec_off = (((size_t)(order + E) - (size_t)d_ws) + 255) & ~(size_t)255;
    unsigned* rec = (unsigned*)((char*)d_ws + rec_off);

    bool full = ws_size >= rec_off + (size_t)E * REC_B;
    int L0;
    if (full) {
        L0 = E;
    } else {
        L0 = ((E / 2) + 255) / 256 * 256;
        if (L0 > E) L0 = E;
    }
    int len0 = L0, len1 = E - L0;
    int maxlen = len0 > len1 ? len0 : len1;
    bool big = ws_size >= rec_off + (size_t)maxlen * REC_B;

    zero_int<<<(N + 255) / 256, 256, 0, stream>>>(cnt, N);
    hist_kernel<<<(E + 255) / 256, 256, 0, stream>>>(eidx, cnt, E);
    scan_bsum<<<nb, 256, 0, stream>>>(cnt, bsum, N);
    scan_bscan<<<1, 1024, 0, stream>>>(bsum, nb);
    scan_final<<<nb, 256, 0, stream>>>(cnt, bsum, off, cur, N);
    scatter_kernel<<<(E + 255) / 256, 256, 0, stream>>>(eidx, cur, order, E);
    node_kernel<<<N, 128, 0, stream>>>(nf, attrs, l1w0, l1w1, scw0, scw1, h4, (float*)d_out);

    if (big) {
        mlp_kernel<<<(len0 + 255) / 256, 256, 0, stream>>>(ee, (const float4*)eattr,
                                                           eidx, order, w0, w1,
                                                           rec, 0, len0, E);
        reduce_kernel<<<(N + 3) / 4, 256, 0, stream>>>(rec, off, (const float4*)h4,
                                                       l2w0, l2w1, (float*)d_out,
                                                       N, 0, len0);
        if (len1 > 0) {
            mlp_kernel<<<(len1 + 255) / 256, 256, 0, stream>>>(ee, (const float4*)eattr,
                                                               eidx, order, w0, w1,
                                                               rec, L0, len1, E);
            reduce_kernel<<<(N + 3) / 4, 256, 0, stream>>>(rec, off, (const float4*)h4,
                                                           l2w0, l2w1, (float*)d_out,
                                                           N, L0, len1);
        }
    } else {
        prep_w1p<<<16, 256, 0, stream>>>(w1, w1p);
        gather_kernel<<<N, 64, 0, stream>>>(ee, (const float4*)eattr, eidx, order, off,
                                            w0, (const float2*)w1p, (const float4*)h4,
                                            l2w0, l2w1, (float*)d_out, E);
    }
}

// Round 7
// 384.571 us; speedup vs baseline: 2.3051x; 1.0365x over previous
//
#include <hip/hip_runtime.h>
#include <math.h>

#define SQRT8_INV  0.35355339059327373f   // 1/sqrt(8)
#define H_SCALE    0.04419417382415922f   // 0.25/sqrt(32)
#define FAN_SC     0.04419417382415922f   // 1/sqrt(32*16)
#define W1_SCALE   0.125f                 // 1/sqrt(64)
#define LIN2_SCALE 0.125f                 // 1/sqrt(64)
#define SQ3_INVF   0.57735026918962576f   // 1/sqrt(3)

// record layout per sorted edge slot: 320 B = 80 uints
//   [0..63]  w-words: word j = pack_bf16(w[j], w[j+64]),  j = 0..63
//   [64..67] eattr float4
//   [68..79] pad
#define REC_U 80
#define REC_B 320

typedef __attribute__((ext_vector_type(8))) short short8;
typedef __attribute__((ext_vector_type(4))) float f32x4;

__device__ __forceinline__ unsigned pack_bf16(float a, float b) {
    unsigned ua = __float_as_uint(a);
    ua += 0x7FFFu + ((ua >> 16) & 1u);          // RNE
    unsigned ub = __float_as_uint(b);
    ub += 0x7FFFu + ((ub >> 16) & 1u);
    return (ua >> 16) | (ub & 0xFFFF0000u);
}
__device__ __forceinline__ short bf16b(float x) {
    unsigned u = __float_as_uint(x);
    u += 0x7FFFu + ((u >> 16) & 1u);
    return (short)(u >> 16);
}
__device__ __forceinline__ float bf_lo(unsigned u) { return __uint_as_float(u << 16); }
__device__ __forceinline__ float bf_hi(unsigned u) { return __uint_as_float(u & 0xFFFF0000u); }

// ---------------- zero int buffer ----------------
__global__ __launch_bounds__(256) void zero_int(int* __restrict__ p, int n) {
    int i = blockIdx.x * 256 + threadIdx.x;
    if (i < n) p[i] = 0;
}

// ---------------- w1 -> w1p (fallback gather path) ----------------
__global__ __launch_bounds__(256) void prep_w1p(const float* __restrict__ w1,
                                                float* __restrict__ w1p) {
    int idx = blockIdx.x * 256 + threadIdx.x;
    if (idx >= 64 * 64) return;
    int j = idx >> 6, t = idx & 63;
    int colA = (t < 32) ? t : t + 32;
    int colB = (t < 32) ? t + 32 : t + 64;
    w1p[idx * 2 + 0] = w1[j * 128 + colA];
    w1p[idx * 2 + 1] = w1[j * 128 + colB];
}

// ---------------- histogram of edge_dst ----------------
__global__ __launch_bounds__(256) void hist_kernel(const int* __restrict__ eidx,
                                                   int* __restrict__ cnt, int E) {
    int e = blockIdx.x * 256 + threadIdx.x;
    if (e < E) atomicAdd(&cnt[eidx[e]], 1);
}

// ---------------- hierarchical scan, stage A: per-block sums ----------------
__global__ __launch_bounds__(256) void scan_bsum(const int* __restrict__ cnt,
                                                 int* __restrict__ bsum, int N) {
    __shared__ int red[256];
    int t = threadIdx.x, i = blockIdx.x * 256 + t;
    red[t] = (i < N) ? cnt[i] : 0;
    __syncthreads();
    #pragma unroll
    for (int d = 128; d > 0; d >>= 1) {
        if (t < d) red[t] += red[t + d];
        __syncthreads();
    }
    if (t == 0) bsum[blockIdx.x] = red[0];
}

// ---------------- stage B: exclusive scan of block sums (nb <= 1024) ----------------
__global__ __launch_bounds__(1024) void scan_bscan(int* __restrict__ bsum, int nb) {
    __shared__ int s[1024];
    int t = threadIdx.x;
    int v = (t < nb) ? bsum[t] : 0;
    s[t] = v;
    __syncthreads();
    for (int d = 1; d < 1024; d <<= 1) {
        int u = (t >= d) ? s[t - d] : 0;
        __syncthreads();
        s[t] += u;
        __syncthreads();
    }
    if (t < nb) bsum[t] = s[t] - v;   // exclusive
}

// ---------------- stage C: in-block scan + base -> off, cur ----------------
__global__ __launch_bounds__(256) void scan_final(const int* __restrict__ cnt,
                                                  const int* __restrict__ bsum,
                                                  int* __restrict__ off,
                                                  int* __restrict__ cur, int N) {
    __shared__ int s[256];
    int t = threadIdx.x, i = blockIdx.x * 256 + t;
    int v = (i < N) ? cnt[i] : 0;
    s[t] = v;
    __syncthreads();
    for (int d = 1; d < 256; d <<= 1) {
        int u = (t >= d) ? s[t - d] : 0;
        __syncthreads();
        s[t] += u;
        __syncthreads();
    }
    int ex = s[t] - v + bsum[blockIdx.x];
    if (i < N) { off[i] = ex; cur[i] = ex; }
    if (i == N - 1) off[N] = ex + v;
}

// ---------------- scatter edge ids + srcs into dst-sorted order ----------------
__global__ __launch_bounds__(256) void scatter_kernel(const int* __restrict__ eidx,
                                                      int* __restrict__ cur,
                                                      int* __restrict__ order,
                                                      int* __restrict__ srcs, int E) {
    int e = blockIdx.x * 256 + threadIdx.x;
    if (e >= E) return;
    int pos = atomicAdd(&cur[eidx[e]], 1);
    order[pos] = e;
    srcs[pos] = eidx[E + e];
}

// ---------------- node stage: h (lin1, interleaved float4) + sc into out ----------------
__global__ __launch_bounds__(128) void node_kernel(
    const float* __restrict__ nf, const float* __restrict__ attrs,
    const float* __restrict__ l1w0, const float* __restrict__ l1w1,
    const float* __restrict__ scw0, const float* __restrict__ scw1,
    float* __restrict__ h4, float* __restrict__ out) {
    int n = blockIdx.x;
    int t = threadIdx.x;
    __shared__ float x[128];
    __shared__ int vs;
    x[t] = nf[n * 128 + t];
    if (t < 16) {
        if (attrs[n * 16 + t] > 0.5f) vs = t;   // one-hot: exactly one writer
    }
    __syncthreads();
    int v = vs;
    if (t < 32) {
        int w = t;
        float a = 0.f, b = 0.f;
        #pragma unroll
        for (int u = 0; u < 32; ++u) {
            float xv = x[u];
            a = fmaf(xv, l1w0[u * 32 + w], a);
            b = fmaf(xv, scw0[u * 512 + v * 32 + w], b);
        }
        h4[n * 128 + w * 4] = a * H_SCALE;
        out[n * 128 + w]    = b * FAN_SC;
    } else {
        int j = t - 32;                // 0..95
        int vch = j / 3, m = j - vch * 3;
        float a = 0.f, b = 0.f;
        #pragma unroll
        for (int u = 0; u < 32; ++u) {
            float xv = x[32 + u * 3 + m];
            a = fmaf(xv, l1w1[u * 32 + vch], a);
            b = fmaf(xv, scw1[u * 512 + v * 32 + vch], b);
        }
        h4[n * 128 + vch * 4 + 1 + m]   = a * H_SCALE;
        out[n * 128 + 32 + vch * 3 + m] = b * FAN_SC;
    }
}

// ---------------- edge MLP: layer1 VALU (chunked) + layer2 MFMA ----------------
__global__ __launch_bounds__(256) void mlp_kernel(
    const float* __restrict__ ee, const float4* __restrict__ eattr4,
    const int* __restrict__ order,
    const float* __restrict__ w0, const float* __restrict__ w1,
    unsigned* __restrict__ rec, int base, int len) {
    __shared__ unsigned amat[256 * 32];     // A-tile: [edge][64 bf16], XOR-swizzled
    int tid  = threadIdx.x;
    int lane = tid & 63, wid = tid >> 6;
    int m = lane & 15, q = lane >> 4;
    int idx  = blockIdx.x * 256 + tid;
    bool valid = idx < len;

    // ---- B fragments (once per block): bf16(w1[k][chan]), k-chunk q*8+i
    short8 bf00, bf01, bf10, bf11;          // [chan tile lo/hi][k-step 0/1]
    {
        int clo = wid * 16 + m, chi = clo + 64;
        #pragma unroll
        for (int i = 0; i < 8; ++i) {
            int k0 = q * 8 + i, k1 = 32 + q * 8 + i;
            bf00[i] = bf16b(w1[k0 * 128 + clo]);
            bf01[i] = bf16b(w1[k1 * 128 + clo]);
            bf10[i] = bf16b(w1[k0 * 128 + chi]);
            bf11[i] = bf16b(w1[k1 * 128 + chi]);
        }
    }

    // ---- gather edge embedding + eattr (issued together, one latency)
    float4 ea = make_float4(0.f, 0.f, 0.f, 0.f);
    float eev[8] = {0.f,0.f,0.f,0.f,0.f,0.f,0.f,0.f};
    if (valid) {
        int e = order[base + idx];
        ea  = eattr4[e];
        const float4* eep = (const float4*)ee;
        float4 e0 = eep[(size_t)e * 2], e1 = eep[(size_t)e * 2 + 1];
        eev[0] = e0.x * SQRT8_INV; eev[1] = e0.y * SQRT8_INV;
        eev[2] = e0.z * SQRT8_INV; eev[3] = e0.w * SQRT8_INV;
        eev[4] = e1.x * SQRT8_INV; eev[5] = e1.y * SQRT8_INV;
        eev[6] = e1.z * SQRT8_INV; eev[7] = e1.w * SQRT8_INV;
    }

    // ---- layer 1 + silu in chunks of 8, pack + stage immediately (low VGPR)
    {
        char* arow = (char*)(amat + tid * 32);
        #pragma unroll
        for (int kc = 0; kc < 8; ++kc) {
            float h[8];
            #pragma unroll
            for (int jj = 0; jj < 8; ++jj) {
                int j = kc * 8 + jj;
                float a = 0.f;
                #pragma unroll
                for (int k = 0; k < 8; ++k) a = fmaf(eev[k], w0[k * 64 + j], a);
                float s = 1.f / (1.f + __expf(-a));
                h[jj] = a * s * W1_SCALE;
            }
            uint4 v = make_uint4(pack_bf16(h[0], h[1]), pack_bf16(h[2], h[3]),
                                 pack_bf16(h[4], h[5]), pack_bf16(h[6], h[7]));
            if (!valid) v = make_uint4(0u, 0u, 0u, 0u);
            *(uint4*)(arow + ((kc * 16) ^ ((tid & 7) << 4))) = v;
        }
    }
    __syncthreads();

    // ---- MFMA: 16 edge-tiles x (lo,hi chan tiles) x K=64
    int jb = wid * 16;
    int blockbase = blockIdx.x * 256;
    for (int et = 0; et < 16; ++et) {
        int row = et * 16 + m;
        const char* abase = (const char*)(amat + row * 32);
        int swz = (row & 7) << 4;
        short8 a0 = *(const short8*)(abase + ((q * 16) ^ swz));
        short8 a1 = *(const short8*)(abase + (((64 + q * 16)) ^ swz));
        f32x4 dlo = {0.f, 0.f, 0.f, 0.f}, dhi = {0.f, 0.f, 0.f, 0.f};
        dlo = __builtin_amdgcn_mfma_f32_16x16x32_bf16(a0, bf00, dlo, 0, 0, 0);
        dlo = __builtin_amdgcn_mfma_f32_16x16x32_bf16(a1, bf01, dlo, 0, 0, 0);
        dhi = __builtin_amdgcn_mfma_f32_16x16x32_bf16(a0, bf10, dhi, 0, 0, 0);
        dhi = __builtin_amdgcn_mfma_f32_16x16x32_bf16(a1, bf11, dhi, 0, 0, 0);
        // D: row(edge-within-tile) = 4*q + i, col(word) = jb + m
        #pragma unroll
        for (int i = 0; i < 4; ++i) {
            int eloc = blockbase + et * 16 + 4 * q + i;
            if (eloc < len)
                rec[(size_t)eloc * REC_U + jb + m] = pack_bf16(dlo[i], dhi[i]);
        }
    }

    // ---- tail field (eattr)
    if (valid) {
        unsigned* myrec = rec + (size_t)idx * REC_U;
        *(float4*)(myrec + 64) = ea;
    }
}

// ---------------- reduce: srcs preloaded per wave, depth-4 static pipeline ----------------
__global__ __launch_bounds__(256) void reduce_kernel(
    const unsigned* __restrict__ rec, const int* __restrict__ off,
    const int* __restrict__ srcs, const float4* __restrict__ h4,
    const float* __restrict__ l2w0, const float* __restrict__ l2w1,
    float* __restrict__ out, int N, int base, int len) {
    int w = threadIdx.x >> 6, t = threadIdx.x & 63;
    int n = blockIdx.x * 4 + w;
    __shared__ float ld[4][256];
    int c = t & 31;
    int half = t >> 5;
    int kk = half ? (c + 32) : c;       // word index this thread consumes
    float acc0 = 0.f, acc1 = 0.f, acc2 = 0.f, acc3 = 0.f;

    int beg = 0, end = 0;
    if (n < N) {
        beg = max(off[n], base);
        end = min(off[n + 1], base + len);
    }

#define REFILL(k, ii) do {                                              \
        int _i = (ii);                                                  \
        if (_i < cnt) {                                                 \
            const unsigned* _r = rec + (size_t)(rbase + _i) * REC_U;    \
            wu##k = _r[kk];                                             \
            ea##k = *(const float4*)(_r + 64);                          \
            int _s = __builtin_amdgcn_readlane(srcv, _i);               \
            xs##k = h4[(size_t)_s * 32 + c];                            \
        }                                                               \
    } while (0)

#define COMPUTE(k) do {                                                 \
        float wlo = bf_lo(wu##k), whi = bf_hi(wu##k);                   \
        float4 _ea = ea##k, _xs = xs##k;                                \
        if (half == 0) {                                                \
            acc0 = fmaf(wlo * _xs.x, _ea.x, acc0);       /* m0a */      \
            float cy = whi * _ea.x;                                     \
            acc1 = fmaf(cy, _xs.y, acc1);                /* m1b */      \
            acc2 = fmaf(cy, _xs.z, acc2);                               \
            acc3 = fmaf(cy, _xs.w, acc3);                               \
        } else {                                                        \
            float bx = wlo * _xs.x;                                     \
            acc1 = fmaf(bx, _ea.y, acc1);                /* m1a */      \
            acc2 = fmaf(bx, _ea.z, acc2);                               \
            acc3 = fmaf(bx, _ea.w, acc3);                               \
            float dv = _xs.y * _ea.y + _xs.z * _ea.z + _xs.w * _ea.w;   \
            acc0 = fmaf(whi * SQ3_INVF, dv, acc0);       /* m0b */      \
        }                                                               \
    } while (0)

    for (int cb = beg; cb < end; cb += 64) {
        int cnt = min(64, end - cb);
        int rbase = cb - base;
        int srcv = (t < cnt) ? srcs[cb + t] : 0;   // all srcs for this chunk, one load
        unsigned wu0 = 0, wu1 = 0, wu2 = 0, wu3 = 0;
        float4 ea0 = make_float4(0,0,0,0), ea1 = ea0, ea2 = ea0, ea3 = ea0;
        float4 xs0 = ea0, xs1 = ea0, xs2 = ea0, xs3 = ea0;
        REFILL(0, 0); REFILL(1, 1); REFILL(2, 2); REFILL(3, 3);
        int i = 0;
        for (; i + 4 <= cnt; i += 4) {
            COMPUTE(0); REFILL(0, i + 4);
            COMPUTE(1); REFILL(1, i + 5);
            COMPUTE(2); REFILL(2, i + 6);
            COMPUTE(3); REFILL(3, i + 7);
        }
        int rem = cnt - i;
        if (rem > 0) COMPUTE(0);
        if (rem > 1) COMPUTE(1);
        if (rem > 2) COMPUTE(2);
    }
#undef REFILL
#undef COMPUTE

    if (n < N) {
        if (half == 0) {
            ld[w][c] = acc0;                             // m0a
            ld[w][160 + c * 3 + 0] = acc1;               // m1b
            ld[w][160 + c * 3 + 1] = acc2;
            ld[w][160 + c * 3 + 2] = acc3;
        } else {
            ld[w][32 + c] = acc0;                        // m0b
            ld[w][64 + c * 3 + 0] = acc1;                // m1a
            ld[w][64 + c * 3 + 1] = acc2;
            ld[w][64 + c * 3 + 2] = acc3;
        }
    }
    __syncthreads();
    if (n < N && end > beg) {
        #pragma unroll
        for (int hh = 0; hh < 2; ++hh) {
            int j = t + hh * 64;
            float acc = 0.f;
            if (j < 32) {
                #pragma unroll
                for (int u = 0; u < 64; ++u) acc = fmaf(ld[w][u], l2w0[u * 32 + j], acc);
            } else {
                int jj = j - 32, vch = jj / 3, m = jj - vch * 3;
                #pragma unroll
                for (int u = 0; u < 64; ++u) acc = fmaf(ld[w][64 + u * 3 + m], l2w1[u * 32 + vch], acc);
            }
            out[(size_t)n * 128 + j] += acc * LIN2_SCALE;
        }
    }
}

// ---------------- FALLBACK (ws too small): round-2 fused gather ----------------
__global__ __launch_bounds__(64) void gather_kernel(
    const float* __restrict__ ee, const float4* __restrict__ eattr4,
    const int* __restrict__ eidx, const int* __restrict__ order,
    const int* __restrict__ off,
    const float* __restrict__ w0, const float2* __restrict__ w1p2,
    const float4* __restrict__ h4,
    const float* __restrict__ l2w0, const float* __restrict__ l2w1,
    float* __restrict__ out, int E) {
    int n = blockIdx.x, t = threadIdx.x;
    int beg = off[n], end = off[n + 1];
    __shared__ float s_ee[8];
    __shared__ float s_hid[64];
    __shared__ float ld[256];
    float acc0 = 0.f, acc1 = 0.f, acc2 = 0.f, acc3 = 0.f;
    int c = t & 31;
    for (int i = beg; i < end; ++i) {
        int e = order[i];
        int src = eidx[E + e];
        if (t < 8) s_ee[t] = ee[e * 8 + t] * SQRT8_INV;
        __syncthreads();
        float a = 0.f;
        #pragma unroll
        for (int k = 0; k < 8; ++k) a = fmaf(s_ee[k], w0[k * 64 + t], a);
        float sg = 1.f / (1.f + __expf(-a));
        __syncthreads();
        s_hid[t] = a * sg * W1_SCALE;
        __syncthreads();
        float wA = 0.f, wB = 0.f;
        #pragma unroll
        for (int j = 0; j < 64; ++j) {
            float2 wv = w1p2[j * 64 + t];
            float hj = s_hid[j];
            wA = fmaf(hj, wv.x, wA);
            wB = fmaf(hj, wv.y, wB);
        }
        float4 xs = h4[(size_t)src * 32 + c];
        float4 ea = eattr4[e];
        if (t < 32) {
            acc0 = fmaf(wA * xs.x, ea.x, acc0);
            float bx = wB * xs.x;
            acc1 = fmaf(bx, ea.y, acc1);
            acc2 = fmaf(bx, ea.z, acc2);
            acc3 = fmaf(bx, ea.w, acc3);
        } else {
            float dv = xs.y * ea.y + xs.z * ea.z + xs.w * ea.w;
            acc0 = fmaf(wB * SQ3_INVF, dv, acc0);
            float cy = wA * ea.x;
            acc1 = fmaf(cy, xs.y, acc1);
            acc2 = fmaf(cy, xs.z, acc2);
            acc3 = fmaf(cy, xs.w, acc3);
        }
    }
    if (t < 32) {
        ld[t] = acc0;
        ld[64 + t * 3 + 0] = acc1;
        ld[64 + t * 3 + 1] = acc2;
        ld[64 + t * 3 + 2] = acc3;
    } else {
        int cc = t - 32;
        ld[32 + cc] = acc0;
        ld[160 + cc * 3 + 0] = acc1;
        ld[160 + cc * 3 + 1] = acc2;
        ld[160 + cc * 3 + 2] = acc3;
    }
    __syncthreads();
    #pragma unroll
    for (int hh = 0; hh < 2; ++hh) {
        int j = t + hh * 64;
        float acc = 0.f;
        if (j < 32) {
            #pragma unroll
            for (int u = 0; u < 64; ++u) acc = fmaf(ld[u], l2w0[u * 32 + j], acc);
        } else {
            int jj = j - 32, vch = jj / 3, m = jj - vch * 3;
            #pragma unroll
            for (int u = 0; u < 64; ++u) acc = fmaf(ld[64 + u * 3 + m], l2w1[u * 32 + vch], acc);
        }
        out[(size_t)n * 128 + j] += acc * LIN2_SCALE;
    }
}

extern "C" void kernel_launch(void* const* d_in, const int* in_sizes, int n_in,
                              void* d_out, int out_size, void* d_ws, size_t ws_size,
                              hipStream_t stream) {
    const float* nf    = (const float*)d_in[0];
    const float* attrs = (const float*)d_in[1];
    const float* eattr = (const float*)d_in[2];
    const float* ee    = (const float*)d_in[3];
    const int*   eidx  = (const int*)d_in[4];
    const float* l1w0  = (const float*)d_in[5];
    const float* l1w1  = (const float*)d_in[6];
    const float* w0    = (const float*)d_in[7];
    const float* w1    = (const float*)d_in[8];
    const float* l2w0  = (const float*)d_in[9];
    const float* l2w1  = (const float*)d_in[10];
    const float* scw0  = (const float*)d_in[11];
    const float* scw1  = (const float*)d_in[12];

    int N = in_sizes[0] / 128;
    int E = in_sizes[3] / 8;
    int nb = (N + 255) / 256;

    // ws layout: h4 | w1p | cnt | off | cur | bsum | order | srcs | rec
    float* h4    = (float*)d_ws;                       // N*128
    float* w1p   = h4 + (size_t)N * 128;               // 8192
    int*   cnt   = (int*)(w1p + 8192);                 // N
    int*   off   = cnt + N;                            // N+1
    int*   cur   = off + N + 1;                        // N
    int*   bsum  = cur + N;                            // nb
    int*   order = bsum + nb;                          // E
    int*   srcs  = order + E;                          // E
    size_t rec_off = (((size_t)(srcs + E) - (size_t)d_ws) + 255) & ~(size_t)255;
    unsigned* rec = (unsigned*)((char*)d_ws + rec_off);

    bool full = ws_size >= rec_off + (size_t)E * REC_B;
    int L0;
    if (full) {
        L0 = E;
    } else {
        L0 = ((E / 2) + 255) / 256 * 256;
        if (L0 > E) L0 = E;
    }
    int len0 = L0, len1 = E - L0;
    int maxlen = len0 > len1 ? len0 : len1;
    bool big = ws_size >= rec_off + (size_t)maxlen * REC_B;

    zero_int<<<(N + 255) / 256, 256, 0, stream>>>(cnt, N);
    hist_kernel<<<(E + 255) / 256, 256, 0, stream>>>(eidx, cnt, E);
    scan_bsum<<<nb, 256, 0, stream>>>(cnt, bsum, N);
    scan_bscan<<<1, 1024, 0, stream>>>(bsum, nb);
    scan_final<<<nb, 256, 0, stream>>>(cnt, bsum, off, cur, N);
    scatter_kernel<<<(E + 255) / 256, 256, 0, stream>>>(eidx, cur, order, srcs, E);
    node_kernel<<<N, 128, 0, stream>>>(nf, attrs, l1w0, l1w1, scw0, scw1, h4, (float*)d_out);

    if (big) {
        mlp_kernel<<<(len0 + 255) / 256, 256, 0, stream>>>(ee, (const float4*)eattr,
                                                           order, w0, w1,
                                                           rec, 0, len0);
        reduce_kernel<<<(N + 3) / 4, 256, 0, stream>>>(rec, off, srcs, (const float4*)h4,
                                                       l2w0, l2w1, (float*)d_out,
                                                       N, 0, len0);
        if (len1 > 0) {
            mlp_kernel<<<(len1 + 255) / 256, 256, 0, stream>>>(ee, (const float4*)eattr,
                                                               order, w0, w1,
                                                               rec, L0, len1);
            reduce_kernel<<<(N + 3) / 4, 256, 0, stream>>>(rec, off, srcs, (const float4*)h4,
                                                           l2w0, l2w1, (float*)d_out,
                                                           N, L0, len1);
        }
    } else {
        prep_w1p<<<16, 256, 0, stream>>>(w1, w1p);
        gather_kernel<<<N, 64, 0, stream>>>(ee, (const float4*)eattr, eidx, order, off,
                                            w0, (const float2*)w1p, (const float4*)h4,
                                            l2w0, l2w1, (float*)d_out, E);
    }
}